// Round 4
// baseline (20911.945 us; speedup 1.0000x reference)
//
#include <hip/hip_runtime.h>

// Problem sizes (fixed by the reference)
#define T_  512
#define B_  64
#define I_  256
#define H_  512
#define G3_ 1536

// Workspace layout (bytes) — total EXACTLY 256 MB.
// scores reuses xproj's memory (xproj dead after scan_kernel).
// The 1 KB barrier lives in d_out (dead until softmax_ctx fully rewrites it).
#define XPROJ_BYTES ((size_t)T_*B_*G3_*4)   // 201,326,592
#define HS_BYTES    ((size_t)T_*B_*H_*4)    //  67,108,864
#define XPROJ_OFF   ((size_t)0)
#define HS_OFF      (XPROJ_OFF + XPROJ_BYTES)
#define SC_OFF      ((size_t)0)             // alias: used only after scan

__device__ __forceinline__ float sigm_f(float x){
  x = fminf(fmaxf(x, -30.f), 30.f);
  return 1.f/(1.f + __expf(-x));
}
__device__ __forceinline__ float tanh_f(float x){
  x = fminf(fmaxf(x, -15.f), 15.f);
  float e = __expf(2.f*x);
  return (e-1.f)/(e+1.f);
}

// ---------------------------------------------------------------------------
// Kernel 0: zero the inter-WG barrier (lives in d_out, re-poisoned each call)
// ---------------------------------------------------------------------------
__global__ void zero_bar(unsigned* __restrict__ bar){
  bar[threadIdx.x] = 0u;
}

// ---------------------------------------------------------------------------
// Kernel 1: x_proj[t][b][g] = sum_i x[b][t][i]*Wih[g][i] + bih[g]
// M=32768 rows (r = t*64+b), N=1536, K=256. 128x128x32 tiles, 8x8 microtile.
// ---------------------------------------------------------------------------
__global__ __launch_bounds__(256, 2) void xproj_gemm(
    const float* __restrict__ x, const float* __restrict__ Wih,
    const float* __restrict__ bih, float* __restrict__ xproj)
{
  __shared__ __align__(16) float As[32][132];
  __shared__ __align__(16) float Bs[32][132];
  const int tid = threadIdx.x;
  const int tx = tid & 15, ty = tid >> 4;
  const int r0 = blockIdx.x * 128;
  const int n0 = blockIdx.y * 128;

  float acc[8][8];
  #pragma unroll
  for (int i=0;i<8;i++)
    #pragma unroll
    for (int j=0;j<8;j++) acc[i][j] = 0.f;

  for (int kt = 0; kt < I_; kt += 32) {
    #pragma unroll
    for (int p = 0; p < 4; p++) {
      int f4 = p*256 + tid;
      int m  = f4 >> 3;          // local row 0..127
      int kf = f4 & 7;           // k-float4 0..7
      int r  = r0 + m;
      // x[b][t][i], b=r&63, t=r>>6
      const float4 va = *(const float4*)(x + (((size_t)(r & 63))*T_ + (size_t)(r >> 6))*I_ + kt + kf*4);
      As[kf*4+0][m]=va.x; As[kf*4+1][m]=va.y; As[kf*4+2][m]=va.z; As[kf*4+3][m]=va.w;
      const float4 vb = *(const float4*)(Wih + ((size_t)(n0 + m))*I_ + kt + kf*4);
      Bs[kf*4+0][m]=vb.x; Bs[kf*4+1][m]=vb.y; Bs[kf*4+2][m]=vb.z; Bs[kf*4+3][m]=vb.w;
    }
    __syncthreads();
    #pragma unroll
    for (int kk=0;kk<32;kk++){
      float a[8], b[8];
      *(float4*)&a[0] = *(const float4*)&As[kk][ty*8];
      *(float4*)&a[4] = *(const float4*)&As[kk][ty*8+4];
      *(float4*)&b[0] = *(const float4*)&Bs[kk][tx*8];
      *(float4*)&b[4] = *(const float4*)&Bs[kk][tx*8+4];
      #pragma unroll
      for (int i=0;i<8;i++)
        #pragma unroll
        for (int j=0;j<8;j++)
          acc[i][j] += a[i]*b[j];
    }
    __syncthreads();
  }
  float bias[8];
  #pragma unroll
  for (int j=0;j<8;j++) bias[j] = bih[n0 + tx*8 + j];
  #pragma unroll
  for (int i=0;i<8;i++){
    float* o = xproj + ((size_t)(r0 + ty*8 + i))*G3_ + n0 + tx*8;
    float4 o0 = { acc[i][0]+bias[0], acc[i][1]+bias[1], acc[i][2]+bias[2], acc[i][3]+bias[3] };
    float4 o1 = { acc[i][4]+bias[4], acc[i][5]+bias[5], acc[i][6]+bias[6], acc[i][7]+bias[7] };
    *(float4*)o = o0; *(float4*)(o+4) = o1;
  }
}

// ---------------------------------------------------------------------------
// Kernel 2: persistent GRU scan.
// 256 WGs x 256 thr. group = bid&7 (XCD-local under %8 dispatch) owns batches
// [8g,8g+8); WG w = bid>>3 owns gate-aligned j-slice [16w,16w+16).
// W_hh rows {j, 512+j, 1024+j} live in VGPRs (96/thread) for all 512 steps.
// h (8x512) lives in LDS; per-step group barrier via agent-scope atomics.
// Thread (rg = tid>>4, kq = tid&15): row j0+rg, k-subset {4kq + 64mq + c}.
// ---------------------------------------------------------------------------
__global__ __launch_bounds__(256, 1) void scan_kernel(
    const float* __restrict__ Whh, const float* __restrict__ bhh,
    const float* __restrict__ xproj, float* __restrict__ hs,
    unsigned* __restrict__ bar)
{
  __shared__ __align__(16) float hl[8*H_];   // 16 KB: h for the 8 batches
  const int tid = threadIdx.x;
  const int bid = blockIdx.x;
  const int grp = bid & 7;
  const int w   = bid >> 3;
  const int b0  = grp * 8;
  const int rg  = tid >> 4;      // 0..15
  const int kq  = tid & 15;      // 0..15
  const int j   = w*16 + rg;

  unsigned* cnt_p = bar + grp*32;
  unsigned* gen_p = bar + grp*32 + 16;

  // zero h
  float4* hl4w = (float4*)hl;
  #pragma unroll
  for (int p=0;p<4;p++) hl4w[p*256+tid] = make_float4(0.f,0.f,0.f,0.f);

  // W_hh -> registers (float4 index kq + mq*16 covers k = 4kq + 64mq + c)
  float4 wr4[8], wz4[8], wn4[8];
  {
    const float4* pr = (const float4*)(Whh + (size_t)j*H_);
    const float4* pz = (const float4*)(Whh + (size_t)(H_+j)*H_);
    const float4* pn = (const float4*)(Whh + (size_t)(2*H_+j)*H_);
    #pragma unroll
    for (int mq=0;mq<8;mq++){ wr4[mq]=pr[kq+mq*16]; wz4[mq]=pz[kq+mq*16]; wn4[mq]=pn[kq+mq*16]; }
  }
  const float br = bhh[j], bz = bhh[H_+j], bn = bhh[2*H_+j];

  __syncthreads();

  const float4* hl4 = (const float4*)hl;

  for (int t=0; t<T_; t++){
    // prefetch x_proj gate inputs early (hidden under the dot loop)
    float xr_[8], xz_[8], xn_[8];
    if (kq==0){
      const float* xp = xproj + ((size_t)t*B_ + b0)*G3_ + j;
      #pragma unroll
      for (int b=0;b<8;b++){
        xr_[b]=xp[(size_t)b*G3_];
        xz_[b]=xp[(size_t)b*G3_+H_];
        xn_[b]=xp[(size_t)b*G3_+2*H_];
      }
    }
    // dots: per-thread partials over 32 k-values for 8 batches x 3 gates
    float ar[8], az[8], an[8];
    #pragma unroll
    for (int b=0;b<8;b++){ ar[b]=0.f; az[b]=0.f; an[b]=0.f; }
    #pragma unroll
    for (int mq=0;mq<8;mq++){
      #pragma unroll
      for (int b=0;b<8;b++){
        const float4 hv = hl4[b*128 + kq + mq*16];   // 16 banks, 4-way bcast: conflict-free
        ar[b] += hv.x*wr4[mq].x + hv.y*wr4[mq].y + hv.z*wr4[mq].z + hv.w*wr4[mq].w;
        az[b] += hv.x*wz4[mq].x + hv.y*wz4[mq].y + hv.z*wz4[mq].z + hv.w*wz4[mq].w;
        an[b] += hv.x*wn4[mq].x + hv.y*wn4[mq].y + hv.z*wn4[mq].z + hv.w*wn4[mq].w;
      }
    }
    // reduce partials across the 16 kq lanes (low 4 bits of lane id)
    #pragma unroll
    for (int b=0;b<8;b++){
      ar[b] += __shfl_xor(ar[b],1,64); ar[b] += __shfl_xor(ar[b],2,64);
      ar[b] += __shfl_xor(ar[b],4,64); ar[b] += __shfl_xor(ar[b],8,64);
      az[b] += __shfl_xor(az[b],1,64); az[b] += __shfl_xor(az[b],2,64);
      az[b] += __shfl_xor(az[b],4,64); az[b] += __shfl_xor(az[b],8,64);
      an[b] += __shfl_xor(an[b],1,64); an[b] += __shfl_xor(an[b],2,64);
      an[b] += __shfl_xor(an[b],4,64); an[b] += __shfl_xor(an[b],8,64);
    }
    // gates + h_new for this WG's j (16 lanes x 8 batches)
    if (kq==0){
      float* hw = hs + ((size_t)t*B_ + b0)*H_ + j;
      #pragma unroll
      for (int b=0;b<8;b++){
        float rr = sigm_f(xr_[b] + ar[b] + br);
        float zz = sigm_f(xz_[b] + az[b] + bz);
        float nn = tanh_f(xn_[b] + rr*(an[b] + bn));
        float ho = hl[b*H_ + j];
        hw[(size_t)b*H_] = (1.f-zz)*nn + zz*ho;
      }
    }
    if (t == T_-1) break;

    // ---- group barrier (32 WGs, sense-reversing, agent scope) ----
    __threadfence();            // release: flush my hs[t] writes to agent scope
    __syncthreads();
    if (tid==0){
      unsigned g = __hip_atomic_load(gen_p, __ATOMIC_RELAXED, __HIP_MEMORY_SCOPE_AGENT);
      unsigned a = __hip_atomic_fetch_add(cnt_p, 1u, __ATOMIC_RELAXED, __HIP_MEMORY_SCOPE_AGENT);
      if (a == 31u){
        __hip_atomic_store(cnt_p, 0u, __ATOMIC_RELAXED, __HIP_MEMORY_SCOPE_AGENT);
        __hip_atomic_store(gen_p, g+1u, __ATOMIC_RELEASE, __HIP_MEMORY_SCOPE_AGENT);
      } else {
        while (__hip_atomic_load(gen_p, __ATOMIC_RELAXED, __HIP_MEMORY_SCOPE_AGENT) == g){
          __builtin_amdgcn_s_sleep(2);
        }
      }
    }
    __syncthreads();
    __threadfence();            // acquire: invalidate stale cache before reading peers' h

    // reload full h (8x512) from hs[t]
    const float4* src = (const float4*)(hs + ((size_t)t*B_ + b0)*H_);
    #pragma unroll
    for (int p=0;p<4;p++) hl4w[p*256+tid] = src[p*256+tid];
    __syncthreads();
  }
}

// ---------------------------------------------------------------------------
// Kernel 3: scores[r] = sum_h' v[h'] * tanh( sum_h hs[r][h]*aW[h'][h] + ab[h'] )
// M=32768 rows, N=512 (reduced, fused), K=512. 128-row tiles, 4 N-subtiles.
// ---------------------------------------------------------------------------
__global__ __launch_bounds__(256, 2) void attn_scores(
    const float* __restrict__ hs, const float* __restrict__ aW,
    const float* __restrict__ ab, const float* __restrict__ av,
    float* __restrict__ scores)
{
  __shared__ __align__(16) float As[32][132];
  __shared__ __align__(16) float Bs[32][132];
  const int tid = threadIdx.x;
  const int tx = tid & 15, ty = tid >> 4;
  const int r0 = blockIdx.x * 128;

  float sacc[8];
  #pragma unroll
  for (int i=0;i<8;i++) sacc[i]=0.f;

  for (int ntl=0; ntl<4; ntl++){
    const int n0 = ntl*128;
    float acc[8][8];
    #pragma unroll
    for (int i=0;i<8;i++)
      #pragma unroll
      for (int j2=0;j2<8;j2++) acc[i][j2]=0.f;

    for (int kt=0; kt<H_; kt+=32){
      #pragma unroll
      for (int p=0;p<4;p++){
        int f4 = p*256+tid; int m = f4>>3; int kf = f4&7;
        const float4 va = *(const float4*)(hs + ((size_t)(r0+m))*H_ + kt + kf*4);
        As[kf*4+0][m]=va.x; As[kf*4+1][m]=va.y; As[kf*4+2][m]=va.z; As[kf*4+3][m]=va.w;
        const float4 vb = *(const float4*)(aW + ((size_t)(n0+m))*H_ + kt + kf*4);
        Bs[kf*4+0][m]=vb.x; Bs[kf*4+1][m]=vb.y; Bs[kf*4+2][m]=vb.z; Bs[kf*4+3][m]=vb.w;
      }
      __syncthreads();
      #pragma unroll
      for (int kk=0;kk<32;kk++){
        float a[8], b[8];
        *(float4*)&a[0] = *(const float4*)&As[kk][ty*8];
        *(float4*)&a[4] = *(const float4*)&As[kk][ty*8+4];
        *(float4*)&b[0] = *(const float4*)&Bs[kk][tx*8];
        *(float4*)&b[4] = *(const float4*)&Bs[kk][tx*8+4];
        #pragma unroll
        for (int i=0;i<8;i++)
          #pragma unroll
          for (int j2=0;j2<8;j2++)
            acc[i][j2] += a[i]*b[j2];
      }
      __syncthreads();
    }
    float vv[8], bb2[8];
    #pragma unroll
    for (int j2=0;j2<8;j2++){ vv[j2]=av[n0+tx*8+j2]; bb2[j2]=ab[n0+tx*8+j2]; }
    #pragma unroll
    for (int i=0;i<8;i++){
      #pragma unroll
      for (int j2=0;j2<8;j2++){
        sacc[i] += tanh_f(acc[i][j2] + bb2[j2]) * vv[j2];
      }
    }
  }
  // reduce over tx (low 4 lane bits)
  #pragma unroll
  for (int i=0;i<8;i++){
    sacc[i] += __shfl_xor(sacc[i],1,64); sacc[i] += __shfl_xor(sacc[i],2,64);
    sacc[i] += __shfl_xor(sacc[i],4,64); sacc[i] += __shfl_xor(sacc[i],8,64);
  }
  if (tx == 0){
    #pragma unroll
    for (int i=0;i<8;i++) scores[r0 + ty*8 + i] = sacc[i];
  }
}

// ---------------------------------------------------------------------------
// Kernel 4: per-batch softmax over t, then context[b][h] = sum_t w[t]*hs[t][b][h]
// ---------------------------------------------------------------------------
__global__ __launch_bounds__(256, 2) void softmax_ctx(
    const float* __restrict__ scores, const float* __restrict__ hs,
    float* __restrict__ out)
{
  const int b = blockIdx.x;
  const int tid = threadIdx.x;
  __shared__ float wl[512];
  __shared__ float rmax[4];
  __shared__ float rsum[4];

  float s0 = scores[(size_t)tid*B_ + b];
  float s1 = scores[(size_t)(tid+256)*B_ + b];
  float mx = fmaxf(s0,s1);
  #pragma unroll
  for (int s=32;s>=1;s>>=1) mx = fmaxf(mx, __shfl_xor(mx, s, 64));
  if ((tid & 63)==0) rmax[tid>>6]=mx;
  __syncthreads();
  mx = fmaxf(fmaxf(rmax[0],rmax[1]), fmaxf(rmax[2],rmax[3]));
  float e0 = __expf(s0-mx), e1 = __expf(s1-mx);
  float sm = e0+e1;
  #pragma unroll
  for (int s=32;s>=1;s>>=1) sm += __shfl_xor(sm, s, 64);
  if ((tid & 63)==0) rsum[tid>>6]=sm;
  __syncthreads();
  sm = rsum[0]+rsum[1]+rsum[2]+rsum[3];
  float inv = 1.f/sm;
  wl[tid] = e0*inv; wl[tid+256] = e1*inv;
  __syncthreads();

  float2 acc = {0.f, 0.f};
  const int h0 = tid*2;
  #pragma unroll 4
  for (int t=0;t<T_;t++){
    float wt = wl[t];
    float2 hv = *(const float2*)(hs + ((size_t)t*B_ + b)*H_ + h0);
    acc.x += wt*hv.x; acc.y += wt*hv.y;
  }
  *(float2*)(out + (size_t)b*H_ + h0) = acc;
}

// ---------------------------------------------------------------------------
extern "C" void kernel_launch(void* const* d_in, const int* in_sizes, int n_in,
                              void* d_out, int out_size, void* d_ws, size_t ws_size,
                              hipStream_t stream)
{
  const float* x   = (const float*)d_in[0];
  const float* Wih = (const float*)d_in[1];
  const float* Whh = (const float*)d_in[2];
  const float* bih = (const float*)d_in[3];
  const float* bhh = (const float*)d_in[4];
  const float* aW  = (const float*)d_in[5];
  const float* ab  = (const float*)d_in[6];
  const float* av  = (const float*)d_in[7];
  float* out = (float*)d_out;

  char* ws = (char*)d_ws;
  float*    xproj = (float*)(ws + XPROJ_OFF);
  float*    hs    = (float*)(ws + HS_OFF);
  float*    sc    = (float*)(ws + SC_OFF);   // aliases xproj (dead after scan)
  unsigned* bar   = (unsigned*)d_out;        // 1 KB, fully overwritten by softmax_ctx

  zero_bar   <<<1,            256, 0, stream>>>(bar);
  xproj_gemm <<<dim3(256,12), 256, 0, stream>>>(x, Wih, bih, xproj);
  scan_kernel<<<256,          256, 0, stream>>>(Whh, bhh, xproj, hs, bar);
  attn_scores<<<dim3(256),    256, 0, stream>>>(hs, aW, ab, av, sc);
  softmax_ctx<<<64,           256, 0, stream>>>(sc, hs, out);
}

// Round 6
// 20833.704 us; speedup vs baseline: 1.0038x; 1.0038x over previous
//
#include <hip/hip_runtime.h>

// Problem sizes (fixed by the reference)
#define T_  512
#define B_  64
#define I_  256
#define H_  512
#define G3_ 1536

// Workspace layout (bytes) — total EXACTLY 256 MB.
// scores reuses xproj's memory (xproj dead after scan_kernel).
// The 32 KB flag-barrier lives in d_out (dead until softmax_ctx rewrites it).
#define XPROJ_BYTES ((size_t)T_*B_*G3_*4)   // 201,326,592
#define HS_BYTES    ((size_t)T_*B_*H_*4)    //  67,108,864
#define XPROJ_OFF   ((size_t)0)
#define HS_OFF      (XPROJ_OFF + XPROJ_BYTES)
#define SC_OFF      ((size_t)0)             // alias: used only after scan

// Barrier: 8 groups x 32 WGs x 32-word (128 B) padded flag slots = 8192 words.
#define BAR_WORDS 8192

__device__ __forceinline__ float sigm_f(float x){
  x = fminf(fmaxf(x, -30.f), 30.f);
  return 1.f/(1.f + __expf(-x));
}
__device__ __forceinline__ float tanh_f(float x){
  x = fminf(fmaxf(x, -15.f), 15.f);
  float e = __expf(2.f*x);
  return (e-1.f)/(e+1.f);
}

// ---------------------------------------------------------------------------
// Kernel 0: zero the flag barrier (lives in d_out, re-poisoned each call)
// ---------------------------------------------------------------------------
__global__ void zero_bar(unsigned* __restrict__ bar){
  bar[blockIdx.x*256 + threadIdx.x] = 0u;
}

// ---------------------------------------------------------------------------
// Kernel 1: x_proj[t][b][g] = sum_i x[b][t][i]*Wih[g][i] + bih[g]
// M=32768 rows (r = t*64+b), N=1536, K=256. 128x128x32 tiles, 8x8 microtile.
// ---------------------------------------------------------------------------
__global__ __launch_bounds__(256, 2) void xproj_gemm(
    const float* __restrict__ x, const float* __restrict__ Wih,
    const float* __restrict__ bih, float* __restrict__ xproj)
{
  __shared__ __align__(16) float As[32][132];
  __shared__ __align__(16) float Bs[32][132];
  const int tid = threadIdx.x;
  const int tx = tid & 15, ty = tid >> 4;
  const int r0 = blockIdx.x * 128;
  const int n0 = blockIdx.y * 128;

  float acc[8][8];
  #pragma unroll
  for (int i=0;i<8;i++)
    #pragma unroll
    for (int j=0;j<8;j++) acc[i][j] = 0.f;

  for (int kt = 0; kt < I_; kt += 32) {
    #pragma unroll
    for (int p = 0; p < 4; p++) {
      int f4 = p*256 + tid;
      int m  = f4 >> 3;          // local row 0..127
      int kf = f4 & 7;           // k-float4 0..7
      int r  = r0 + m;
      // x[b][t][i], b=r&63, t=r>>6
      const float4 va = *(const float4*)(x + (((size_t)(r & 63))*T_ + (size_t)(r >> 6))*I_ + kt + kf*4);
      As[kf*4+0][m]=va.x; As[kf*4+1][m]=va.y; As[kf*4+2][m]=va.z; As[kf*4+3][m]=va.w;
      const float4 vb = *(const float4*)(Wih + ((size_t)(n0 + m))*I_ + kt + kf*4);
      Bs[kf*4+0][m]=vb.x; Bs[kf*4+1][m]=vb.y; Bs[kf*4+2][m]=vb.z; Bs[kf*4+3][m]=vb.w;
    }
    __syncthreads();
    #pragma unroll
    for (int kk=0;kk<32;kk++){
      float a[8], b[8];
      *(float4*)&a[0] = *(const float4*)&As[kk][ty*8];
      *(float4*)&a[4] = *(const float4*)&As[kk][ty*8+4];
      *(float4*)&b[0] = *(const float4*)&Bs[kk][tx*8];
      *(float4*)&b[4] = *(const float4*)&Bs[kk][tx*8+4];
      #pragma unroll
      for (int i=0;i<8;i++)
        #pragma unroll
        for (int j=0;j<8;j++)
          acc[i][j] += a[i]*b[j];
    }
    __syncthreads();
  }
  float bias[8];
  #pragma unroll
  for (int j=0;j<8;j++) bias[j] = bih[n0 + tx*8 + j];
  #pragma unroll
  for (int i=0;i<8;i++){
    float* o = xproj + ((size_t)(r0 + ty*8 + i))*G3_ + n0 + tx*8;
    float4 o0 = { acc[i][0]+bias[0], acc[i][1]+bias[1], acc[i][2]+bias[2], acc[i][3]+bias[3] };
    float4 o1 = { acc[i][4]+bias[4], acc[i][5]+bias[5], acc[i][6]+bias[6], acc[i][7]+bias[7] };
    *(float4*)o = o0; *(float4*)(o+4) = o1;
  }
}

// ---------------------------------------------------------------------------
// Kernel 2: persistent GRU scan.
// 256 WGs x 256 thr. group = bid&7 owns batches [8g,8g+8); WG w = bid>>3 owns
// gate-aligned j-slice [16w,16w+16). W_hh rows {j,512+j,1024+j} in VGPRs.
// h (8x512) in LDS. Per-step FLAG-ARRAY barrier: each WG store-releases its
// generation to a padded slot; 32 lanes poll all 32 flags in parallel.
// (Round-4 lesson: 32 serialized cross-XCD atomic RMWs cost ~38 us/step.)
// ---------------------------------------------------------------------------
__global__ __launch_bounds__(256, 1) void scan_kernel(
    const float* __restrict__ Whh, const float* __restrict__ bhh,
    const float* __restrict__ xproj, float* __restrict__ hs,
    unsigned* __restrict__ bar)
{
  __shared__ __align__(16) float hl[8*H_];   // 16 KB: h for the 8 batches
  const int tid = threadIdx.x;
  const int bid = blockIdx.x;
  const int grp = bid & 7;
  const int w   = bid >> 3;
  const int b0  = grp * 8;
  const int rg  = tid >> 4;      // 0..15
  const int kq  = tid & 15;      // 0..15
  const int j   = w*16 + rg;

  unsigned* flags  = bar + (size_t)grp*1024;   // 32 slots x 32 words (128 B)
  unsigned* flag_p = flags + (size_t)w*32;

  // zero h
  float4* hl4w = (float4*)hl;
  #pragma unroll
  for (int p=0;p<4;p++) hl4w[p*256+tid] = make_float4(0.f,0.f,0.f,0.f);

  // W_hh -> registers (float4 index kq + mq*16 covers k = 4kq + 64mq + c)
  float4 wr4[8], wz4[8], wn4[8];
  {
    const float4* pr = (const float4*)(Whh + (size_t)j*H_);
    const float4* pz = (const float4*)(Whh + (size_t)(H_+j)*H_);
    const float4* pn = (const float4*)(Whh + (size_t)(2*H_+j)*H_);
    #pragma unroll
    for (int mq=0;mq<8;mq++){ wr4[mq]=pr[kq+mq*16]; wz4[mq]=pz[kq+mq*16]; wn4[mq]=pn[kq+mq*16]; }
  }
  const float br = bhh[j], bz = bhh[H_+j], bn = bhh[2*H_+j];

  __syncthreads();

  const float4* hl4 = (const float4*)hl;

  for (int t=0; t<T_; t++){
    // prefetch x_proj gate inputs early (hidden under the dot loop)
    float xr_[8], xz_[8], xn_[8];
    if (kq==0){
      const float* xp = xproj + ((size_t)t*B_ + b0)*G3_ + j;
      #pragma unroll
      for (int b=0;b<8;b++){
        xr_[b]=xp[(size_t)b*G3_];
        xz_[b]=xp[(size_t)b*G3_+H_];
        xn_[b]=xp[(size_t)b*G3_+2*H_];
      }
    }
    // dots: per-thread partials over 32 k-values for 8 batches x 3 gates
    float ar[8], az[8], an[8];
    #pragma unroll
    for (int b=0;b<8;b++){ ar[b]=0.f; az[b]=0.f; an[b]=0.f; }
    #pragma unroll
    for (int mq=0;mq<8;mq++){
      #pragma unroll
      for (int b=0;b<8;b++){
        const float4 hv = hl4[b*128 + kq + mq*16];   // 16 banks, 4-way bcast: conflict-free
        ar[b] += hv.x*wr4[mq].x + hv.y*wr4[mq].y + hv.z*wr4[mq].z + hv.w*wr4[mq].w;
        az[b] += hv.x*wz4[mq].x + hv.y*wz4[mq].y + hv.z*wz4[mq].z + hv.w*wz4[mq].w;
        an[b] += hv.x*wn4[mq].x + hv.y*wn4[mq].y + hv.z*wn4[mq].z + hv.w*wn4[mq].w;
      }
    }
    // reduce partials across the 16 kq lanes (low 4 bits of lane id)
    #pragma unroll
    for (int b=0;b<8;b++){
      ar[b] += __shfl_xor(ar[b],1,64); ar[b] += __shfl_xor(ar[b],2,64);
      ar[b] += __shfl_xor(ar[b],4,64); ar[b] += __shfl_xor(ar[b],8,64);
      az[b] += __shfl_xor(az[b],1,64); az[b] += __shfl_xor(az[b],2,64);
      az[b] += __shfl_xor(az[b],4,64); az[b] += __shfl_xor(az[b],8,64);
      an[b] += __shfl_xor(an[b],1,64); an[b] += __shfl_xor(an[b],2,64);
      an[b] += __shfl_xor(an[b],4,64); an[b] += __shfl_xor(an[b],8,64);
    }
    // gates + h_new for this WG's j (16 lanes x 8 batches)
    if (kq==0){
      float* hw = hs + ((size_t)t*B_ + b0)*H_ + j;
      #pragma unroll
      for (int b=0;b<8;b++){
        float rr = sigm_f(xr_[b] + ar[b] + br);
        float zz = sigm_f(xz_[b] + az[b] + bz);
        float nn = tanh_f(xn_[b] + rr*(an[b] + bn));
        float ho = hl[b*H_ + j];
        hw[(size_t)b*H_] = (1.f-zz)*nn + zz*ho;
      }
    }
    if (t == T_-1) break;

    // ---- group barrier v2: flag array, parallel arrive + parallel poll ----
    __threadfence();            // release: my hs[t] stores visible agent-wide
    __syncthreads();            // all WG stores ordered before tid0's flag
    const unsigned gen = (unsigned)t + 1u;
    if (tid == 0)
      __hip_atomic_store(flag_p, gen, __ATOMIC_RELEASE, __HIP_MEMORY_SCOPE_AGENT);
    if (tid < 32){
      const unsigned* fp = flags + (size_t)tid*32;
      while (__hip_atomic_load(fp, __ATOMIC_RELAXED, __HIP_MEMORY_SCOPE_AGENT) < gen)
        __builtin_amdgcn_s_sleep(1);
    }
    __syncthreads();
    __threadfence();            // acquire: no stale h before reading peers'

    // reload full h (8x512) from hs[t]
    const float4* src = (const float4*)(hs + ((size_t)t*B_ + b0)*H_);
    #pragma unroll
    for (int p=0;p<4;p++) hl4w[p*256+tid] = src[p*256+tid];
    __syncthreads();
  }
}

// ---------------------------------------------------------------------------
// Kernel 3: scores[r] = sum_h' v[h'] * tanh( sum_h hs[r][h]*aW[h'][h] + ab[h'] )
// M=32768 rows, N=512 (reduced, fused), K=512. 128-row tiles, 4 N-subtiles.
// ---------------------------------------------------------------------------
__global__ __launch_bounds__(256, 2) void attn_scores(
    const float* __restrict__ hs, const float* __restrict__ aW,
    const float* __restrict__ ab, const float* __restrict__ av,
    float* __restrict__ scores)
{
  __shared__ __align__(16) float As[32][132];
  __shared__ __align__(16) float Bs[32][132];
  const int tid = threadIdx.x;
  const int tx = tid & 15, ty = tid >> 4;
  const int r0 = blockIdx.x * 128;

  float sacc[8];
  #pragma unroll
  for (int i=0;i<8;i++) sacc[i]=0.f;

  for (int ntl=0; ntl<4; ntl++){
    const int n0 = ntl*128;
    float acc[8][8];
    #pragma unroll
    for (int i=0;i<8;i++)
      #pragma unroll
      for (int j2=0;j2<8;j2++) acc[i][j2]=0.f;

    for (int kt=0; kt<H_; kt+=32){
      #pragma unroll
      for (int p=0;p<4;p++){
        int f4 = p*256+tid; int m = f4>>3; int kf = f4&7;
        const float4 va = *(const float4*)(hs + ((size_t)(r0+m))*H_ + kt + kf*4);
        As[kf*4+0][m]=va.x; As[kf*4+1][m]=va.y; As[kf*4+2][m]=va.z; As[kf*4+3][m]=va.w;
        const float4 vb = *(const float4*)(aW + ((size_t)(n0+m))*H_ + kt + kf*4);
        Bs[kf*4+0][m]=vb.x; Bs[kf*4+1][m]=vb.y; Bs[kf*4+2][m]=vb.z; Bs[kf*4+3][m]=vb.w;
      }
      __syncthreads();
      #pragma unroll
      for (int kk=0;kk<32;kk++){
        float a[8], b[8];
        *(float4*)&a[0] = *(const float4*)&As[kk][ty*8];
        *(float4*)&a[4] = *(const float4*)&As[kk][ty*8+4];
        *(float4*)&b[0] = *(const float4*)&Bs[kk][tx*8];
        *(float4*)&b[4] = *(const float4*)&Bs[kk][tx*8+4];
        #pragma unroll
        for (int i=0;i<8;i++)
          #pragma unroll
          for (int j2=0;j2<8;j2++)
            acc[i][j2] += a[i]*b[j2];
      }
      __syncthreads();
    }
    float vv[8], bb2[8];
    #pragma unroll
    for (int j2=0;j2<8;j2++){ vv[j2]=av[n0+tx*8+j2]; bb2[j2]=ab[n0+tx*8+j2]; }
    #pragma unroll
    for (int i=0;i<8;i++){
      #pragma unroll
      for (int j2=0;j2<8;j2++){
        sacc[i] += tanh_f(acc[i][j2] + bb2[j2]) * vv[j2];
      }
    }
  }
  // reduce over tx (low 4 lane bits)
  #pragma unroll
  for (int i=0;i<8;i++){
    sacc[i] += __shfl_xor(sacc[i],1,64); sacc[i] += __shfl_xor(sacc[i],2,64);
    sacc[i] += __shfl_xor(sacc[i],4,64); sacc[i] += __shfl_xor(sacc[i],8,64);
  }
  if (tx == 0){
    #pragma unroll
    for (int i=0;i<8;i++) scores[r0 + ty*8 + i] = sacc[i];
  }
}

// ---------------------------------------------------------------------------
// Kernel 4: per-batch softmax over t, then context[b][h] = sum_t w[t]*hs[t][b][h]
// ---------------------------------------------------------------------------
__global__ __launch_bounds__(256, 2) void softmax_ctx(
    const float* __restrict__ scores, const float* __restrict__ hs,
    float* __restrict__ out)
{
  const int b = blockIdx.x;
  const int tid = threadIdx.x;
  __shared__ float wl[512];
  __shared__ float rmax[4];
  __shared__ float rsum[4];

  float s0 = scores[(size_t)tid*B_ + b];
  float s1 = scores[(size_t)(tid+256)*B_ + b];
  float mx = fmaxf(s0,s1);
  #pragma unroll
  for (int s=32;s>=1;s>>=1) mx = fmaxf(mx, __shfl_xor(mx, s, 64));
  if ((tid & 63)==0) rmax[tid>>6]=mx;
  __syncthreads();
  mx = fmaxf(fmaxf(rmax[0],rmax[1]), fmaxf(rmax[2],rmax[3]));
  float e0 = __expf(s0-mx), e1 = __expf(s1-mx);
  float sm = e0+e1;
  #pragma unroll
  for (int s=32;s>=1;s>>=1) sm += __shfl_xor(sm, s, 64);
  if ((tid & 63)==0) rsum[tid>>6]=sm;
  __syncthreads();
  sm = rsum[0]+rsum[1]+rsum[2]+rsum[3];
  float inv = 1.f/sm;
  wl[tid] = e0*inv; wl[tid+256] = e1*inv;
  __syncthreads();

  float2 acc = {0.f, 0.f};
  const int h0 = tid*2;
  #pragma unroll 4
  for (int t=0;t<T_;t++){
    float wt = wl[t];
    float2 hv = *(const float2*)(hs + ((size_t)t*B_ + b)*H_ + h0);
    acc.x += wt*hv.x; acc.y += wt*hv.y;
  }
  *(float2*)(out + (size_t)b*H_ + h0) = acc;
}

// ---------------------------------------------------------------------------
extern "C" void kernel_launch(void* const* d_in, const int* in_sizes, int n_in,
                              void* d_out, int out_size, void* d_ws, size_t ws_size,
                              hipStream_t stream)
{
  const float* x   = (const float*)d_in[0];
  const float* Wih = (const float*)d_in[1];
  const float* Whh = (const float*)d_in[2];
  const float* bih = (const float*)d_in[3];
  const float* bhh = (const float*)d_in[4];
  const float* aW  = (const float*)d_in[5];
  const float* ab  = (const float*)d_in[6];
  const float* av  = (const float*)d_in[7];
  float* out = (float*)d_out;

  char* ws = (char*)d_ws;
  float*    xproj = (float*)(ws + XPROJ_OFF);
  float*    hs    = (float*)(ws + HS_OFF);
  float*    sc    = (float*)(ws + SC_OFF);   // aliases xproj (dead after scan)
  unsigned* bar   = (unsigned*)d_out;        // 32 KB, fully overwritten by softmax_ctx

  zero_bar   <<<BAR_WORDS/256, 256, 0, stream>>>(bar);
  xproj_gemm <<<dim3(256,12),  256, 0, stream>>>(x, Wih, bih, xproj);
  scan_kernel<<<256,           256, 0, stream>>>(Whh, bhh, xproj, hs, bar);
  attn_scores<<<dim3(256),     256, 0, stream>>>(hs, aW, ab, av, sc);
  softmax_ctx<<<64,            256, 0, stream>>>(sc, hs, out);
}

// Round 7
// 5475.988 us; speedup vs baseline: 3.8188x; 3.8046x over previous
//
#include <hip/hip_runtime.h>

// Problem sizes (fixed by the reference)
#define T_  512
#define B_  64
#define I_  256
#define H_  512
#define G3_ 1536

// Workspace layout (bytes) — total EXACTLY 256 MB.
// scores reuses xproj's memory (xproj dead after scan_kernel).
// The 32 KB flag-barrier lives in d_out (dead until softmax_ctx rewrites it).
#define XPROJ_BYTES ((size_t)T_*B_*G3_*4)   // 201,326,592
#define HS_BYTES    ((size_t)T_*B_*H_*4)    //  67,108,864
#define XPROJ_OFF   ((size_t)0)
#define HS_OFF      (XPROJ_OFF + XPROJ_BYTES)
#define SC_OFF      ((size_t)0)             // alias: used only after scan

// Barrier: 8 groups x 32 WGs x 32-word (128 B) padded flag slots = 8192 words.
#define BAR_WORDS 8192

__device__ __forceinline__ float sigm_f(float x){
  x = fminf(fmaxf(x, -30.f), 30.f);
  return 1.f/(1.f + __expf(-x));
}
__device__ __forceinline__ float tanh_f(float x){
  x = fminf(fmaxf(x, -15.f), 15.f);
  float e = __expf(2.f*x);
  return (e-1.f)/(e+1.f);
}

// ---------------------------------------------------------------------------
// Kernel 0: zero the flag barrier (lives in d_out, re-poisoned each call)
// ---------------------------------------------------------------------------
__global__ void zero_bar(unsigned* __restrict__ bar){
  bar[blockIdx.x*256 + threadIdx.x] = 0u;
}

// ---------------------------------------------------------------------------
// Kernel 1: x_proj[t][b][g] = sum_i x[b][t][i]*Wih[g][i] + bih[g]
// M=32768 rows (r = t*64+b), N=1536, K=256. 128x128x32 tiles, 8x8 microtile.
// ---------------------------------------------------------------------------
__global__ __launch_bounds__(256, 2) void xproj_gemm(
    const float* __restrict__ x, const float* __restrict__ Wih,
    const float* __restrict__ bih, float* __restrict__ xproj)
{
  __shared__ __align__(16) float As[32][132];
  __shared__ __align__(16) float Bs[32][132];
  const int tid = threadIdx.x;
  const int tx = tid & 15, ty = tid >> 4;
  const int r0 = blockIdx.x * 128;
  const int n0 = blockIdx.y * 128;

  float acc[8][8];
  #pragma unroll
  for (int i=0;i<8;i++)
    #pragma unroll
    for (int j=0;j<8;j++) acc[i][j] = 0.f;

  for (int kt = 0; kt < I_; kt += 32) {
    #pragma unroll
    for (int p = 0; p < 4; p++) {
      int f4 = p*256 + tid;
      int m  = f4 >> 3;          // local row 0..127
      int kf = f4 & 7;           // k-float4 0..7
      int r  = r0 + m;
      // x[b][t][i], b=r&63, t=r>>6
      const float4 va = *(const float4*)(x + (((size_t)(r & 63))*T_ + (size_t)(r >> 6))*I_ + kt + kf*4);
      As[kf*4+0][m]=va.x; As[kf*4+1][m]=va.y; As[kf*4+2][m]=va.z; As[kf*4+3][m]=va.w;
      const float4 vb = *(const float4*)(Wih + ((size_t)(n0 + m))*I_ + kt + kf*4);
      Bs[kf*4+0][m]=vb.x; Bs[kf*4+1][m]=vb.y; Bs[kf*4+2][m]=vb.z; Bs[kf*4+3][m]=vb.w;
    }
    __syncthreads();
    #pragma unroll
    for (int kk=0;kk<32;kk++){
      float a[8], b[8];
      *(float4*)&a[0] = *(const float4*)&As[kk][ty*8];
      *(float4*)&a[4] = *(const float4*)&As[kk][ty*8+4];
      *(float4*)&b[0] = *(const float4*)&Bs[kk][tx*8];
      *(float4*)&b[4] = *(const float4*)&Bs[kk][tx*8+4];
      #pragma unroll
      for (int i=0;i<8;i++)
        #pragma unroll
        for (int j=0;j<8;j++)
          acc[i][j] += a[i]*b[j];
    }
    __syncthreads();
  }
  float bias[8];
  #pragma unroll
  for (int j=0;j<8;j++) bias[j] = bih[n0 + tx*8 + j];
  #pragma unroll
  for (int i=0;i<8;i++){
    float* o = xproj + ((size_t)(r0 + ty*8 + i))*G3_ + n0 + tx*8;
    float4 o0 = { acc[i][0]+bias[0], acc[i][1]+bias[1], acc[i][2]+bias[2], acc[i][3]+bias[3] };
    float4 o1 = { acc[i][4]+bias[4], acc[i][5]+bias[5], acc[i][6]+bias[6], acc[i][7]+bias[7] };
    *(float4*)o = o0; *(float4*)(o+4) = o1;
  }
}

// ---------------------------------------------------------------------------
// Kernel 2: persistent GRU scan.
// 256 WGs x 256 thr. group = bid&7 owns batches [8g,8g+8); WG w = bid>>3 owns
// gate-aligned j-slice [16w,16w+16). W_hh rows {j,512+j,1024+j} in VGPRs.
// h (8x512) in LDS.
// Sync v3 (R6 lesson: flag-array vs RMW barrier was NEUTRAL at ~40us/step —
// the cost is the per-step __threadfence pair => buffer_wbl2/buffer_inv full
// L2 tag-walks on every wave). Fix: NO fences in the loop. h is exchanged
// via agent-scope RELAXED atomics, which bypass L1/L2 (sc0 sc1) and hit the
// device coherence point (memory-side Infinity Cache). Ordering is by HW:
// __syncthreads() drains vmcnt(0) before s_barrier, so data stores are
// complete before tid0's flag store; pollers' reloads issue after the flag
// load by control dependency and read the coherence point directly.
// ---------------------------------------------------------------------------
__global__ __launch_bounds__(256, 1) void scan_kernel(
    const float* __restrict__ Whh, const float* __restrict__ bhh,
    const float* __restrict__ xproj, float* __restrict__ hs,
    unsigned* __restrict__ bar)
{
  __shared__ __align__(16) float hl[8*H_];   // 16 KB: h for the 8 batches
  const int tid = threadIdx.x;
  const int bid = blockIdx.x;
  const int grp = bid & 7;
  const int w   = bid >> 3;
  const int b0  = grp * 8;
  const int rg  = tid >> 4;      // 0..15
  const int kq  = tid & 15;      // 0..15
  const int j   = w*16 + rg;

  unsigned* flags  = bar + (size_t)grp*1024;   // 32 slots x 32 words (128 B)
  unsigned* flag_p = flags + (size_t)w*32;

  // zero h
  float4* hl4w = (float4*)hl;
  #pragma unroll
  for (int p=0;p<4;p++) hl4w[p*256+tid] = make_float4(0.f,0.f,0.f,0.f);

  // W_hh -> registers (float4 index kq + mq*16 covers k = 4kq + 64mq + c)
  float4 wr4[8], wz4[8], wn4[8];
  {
    const float4* pr = (const float4*)(Whh + (size_t)j*H_);
    const float4* pz = (const float4*)(Whh + (size_t)(H_+j)*H_);
    const float4* pn = (const float4*)(Whh + (size_t)(2*H_+j)*H_);
    #pragma unroll
    for (int mq=0;mq<8;mq++){ wr4[mq]=pr[kq+mq*16]; wz4[mq]=pz[kq+mq*16]; wn4[mq]=pn[kq+mq*16]; }
  }
  const float br = bhh[j], bz = bhh[H_+j], bn = bhh[2*H_+j];

  __syncthreads();

  const float4* hl4 = (const float4*)hl;

  for (int t=0; t<T_; t++){
    // prefetch x_proj gate inputs early (hidden under the dot loop)
    float xr_[8], xz_[8], xn_[8];
    if (kq==0){
      const float* xp = xproj + ((size_t)t*B_ + b0)*G3_ + j;
      #pragma unroll
      for (int b=0;b<8;b++){
        xr_[b]=xp[(size_t)b*G3_];
        xz_[b]=xp[(size_t)b*G3_+H_];
        xn_[b]=xp[(size_t)b*G3_+2*H_];
      }
    }
    // dots: per-thread partials over 32 k-values for 8 batches x 3 gates
    float ar[8], az[8], an[8];
    #pragma unroll
    for (int b=0;b<8;b++){ ar[b]=0.f; az[b]=0.f; an[b]=0.f; }
    #pragma unroll
    for (int mq=0;mq<8;mq++){
      #pragma unroll
      for (int b=0;b<8;b++){
        const float4 hv = hl4[b*128 + kq + mq*16];   // 16 banks, 4-way bcast: conflict-free
        ar[b] += hv.x*wr4[mq].x + hv.y*wr4[mq].y + hv.z*wr4[mq].z + hv.w*wr4[mq].w;
        az[b] += hv.x*wz4[mq].x + hv.y*wz4[mq].y + hv.z*wz4[mq].z + hv.w*wz4[mq].w;
        an[b] += hv.x*wn4[mq].x + hv.y*wn4[mq].y + hv.z*wn4[mq].z + hv.w*wn4[mq].w;
      }
    }
    // reduce partials across the 16 kq lanes (low 4 bits of lane id)
    #pragma unroll
    for (int b=0;b<8;b++){
      ar[b] += __shfl_xor(ar[b],1,64); ar[b] += __shfl_xor(ar[b],2,64);
      ar[b] += __shfl_xor(ar[b],4,64); ar[b] += __shfl_xor(ar[b],8,64);
      az[b] += __shfl_xor(az[b],1,64); az[b] += __shfl_xor(az[b],2,64);
      az[b] += __shfl_xor(az[b],4,64); az[b] += __shfl_xor(az[b],8,64);
      an[b] += __shfl_xor(an[b],1,64); an[b] += __shfl_xor(an[b],2,64);
      an[b] += __shfl_xor(an[b],4,64); an[b] += __shfl_xor(an[b],8,64);
    }
    // gates + h_new for this WG's j (16 lanes x 8 batches).
    // h_new goes out as agent-scope relaxed atomic stores: write-through to
    // the device coherence point, no L2 dirty lines -> nothing to fence.
    if (kq==0){
      float* hw = hs + ((size_t)t*B_ + b0)*H_ + j;
      #pragma unroll
      for (int b=0;b<8;b++){
        float rr = sigm_f(xr_[b] + ar[b] + br);
        float zz = sigm_f(xz_[b] + az[b] + bz);
        float nn = tanh_f(xn_[b] + rr*(an[b] + bn));
        float ho = hl[b*H_ + j];
        __hip_atomic_store(hw + (size_t)b*H_, (1.f-zz)*nn + zz*ho,
                           __ATOMIC_RELAXED, __HIP_MEMORY_SCOPE_AGENT);
      }
    }
    if (t == T_-1) break;

    // ---- sync v3: no fences. syncthreads drains vmcnt(0) (data stores
    // complete), then flag store, parallel poll, then bypass reload. ----
    __syncthreads();
    const unsigned gen = (unsigned)t + 1u;
    if (tid == 0)
      __hip_atomic_store(flag_p, gen, __ATOMIC_RELAXED, __HIP_MEMORY_SCOPE_AGENT);
    if (tid < 32){
      unsigned* fp = flags + (size_t)tid*32;
      while (__hip_atomic_load(fp, __ATOMIC_RELAXED, __HIP_MEMORY_SCOPE_AGENT) < gen)
        __builtin_amdgcn_s_sleep(1);
    }
    __syncthreads();

    // reload full h (8x512 = 2048 x 8B) via coherence-point bypass loads
    {
      unsigned long long* src = (unsigned long long*)(hs + ((size_t)t*B_ + b0)*H_);
      unsigned long long* dst = (unsigned long long*)hl;
      #pragma unroll
      for (int p=0;p<8;p++)
        dst[p*256+tid] = __hip_atomic_load(src + p*256 + tid,
                                           __ATOMIC_RELAXED, __HIP_MEMORY_SCOPE_AGENT);
    }
    __syncthreads();
  }
}

// ---------------------------------------------------------------------------
// Kernel 3: scores[r] = sum_h' v[h'] * tanh( sum_h hs[r][h]*aW[h'][h] + ab[h'] )
// M=32768 rows, N=512 (reduced, fused), K=512. 128-row tiles, 4 N-subtiles.
// ---------------------------------------------------------------------------
__global__ __launch_bounds__(256, 2) void attn_scores(
    const float* __restrict__ hs, const float* __restrict__ aW,
    const float* __restrict__ ab, const float* __restrict__ av,
    float* __restrict__ scores)
{
  __shared__ __align__(16) float As[32][132];
  __shared__ __align__(16) float Bs[32][132];
  const int tid = threadIdx.x;
  const int tx = tid & 15, ty = tid >> 4;
  const int r0 = blockIdx.x * 128;

  float sacc[8];
  #pragma unroll
  for (int i=0;i<8;i++) sacc[i]=0.f;

  for (int ntl=0; ntl<4; ntl++){
    const int n0 = ntl*128;
    float acc[8][8];
    #pragma unroll
    for (int i=0;i<8;i++)
      #pragma unroll
      for (int j2=0;j2<8;j2++) acc[i][j2]=0.f;

    for (int kt=0; kt<H_; kt+=32){
      #pragma unroll
      for (int p=0;p<4;p++){
        int f4 = p*256+tid; int m = f4>>3; int kf = f4&7;
        const float4 va = *(const float4*)(hs + ((size_t)(r0+m))*H_ + kt + kf*4);
        As[kf*4+0][m]=va.x; As[kf*4+1][m]=va.y; As[kf*4+2][m]=va.z; As[kf*4+3][m]=va.w;
        const float4 vb = *(const float4*)(aW + ((size_t)(n0+m))*H_ + kt + kf*4);
        Bs[kf*4+0][m]=vb.x; Bs[kf*4+1][m]=vb.y; Bs[kf*4+2][m]=vb.z; Bs[kf*4+3][m]=vb.w;
      }
      __syncthreads();
      #pragma unroll
      for (int kk=0;kk<32;kk++){
        float a[8], b[8];
        *(float4*)&a[0] = *(const float4*)&As[kk][ty*8];
        *(float4*)&a[4] = *(const float4*)&As[kk][ty*8+4];
        *(float4*)&b[0] = *(const float4*)&Bs[kk][tx*8];
        *(float4*)&b[4] = *(const float4*)&Bs[kk][tx*8+4];
        #pragma unroll
        for (int i=0;i<8;i++)
          #pragma unroll
          for (int j2=0;j2<8;j2++)
            acc[i][j2] += a[i]*b[j2];
      }
      __syncthreads();
    }
    float vv[8], bb2[8];
    #pragma unroll
    for (int j2=0;j2<8;j2++){ vv[j2]=av[n0+tx*8+j2]; bb2[j2]=ab[n0+tx*8+j2]; }
    #pragma unroll
    for (int i=0;i<8;i++){
      #pragma unroll
      for (int j2=0;j2<8;j2++){
        sacc[i] += tanh_f(acc[i][j2] + bb2[j2]) * vv[j2];
      }
    }
  }
  // reduce over tx (low 4 lane bits)
  #pragma unroll
  for (int i=0;i<8;i++){
    sacc[i] += __shfl_xor(sacc[i],1,64); sacc[i] += __shfl_xor(sacc[i],2,64);
    sacc[i] += __shfl_xor(sacc[i],4,64); sacc[i] += __shfl_xor(sacc[i],8,64);
  }
  if (tx == 0){
    #pragma unroll
    for (int i=0;i<8;i++) scores[r0 + ty*8 + i] = sacc[i];
  }
}

// ---------------------------------------------------------------------------
// Kernel 4: per-batch softmax over t, then context[b][h] = sum_t w[t]*hs[t][b][h]
// ---------------------------------------------------------------------------
__global__ __launch_bounds__(256, 2) void softmax_ctx(
    const float* __restrict__ scores, const float* __restrict__ hs,
    float* __restrict__ out)
{
  const int b = blockIdx.x;
  const int tid = threadIdx.x;
  __shared__ float wl[512];
  __shared__ float rmax[4];
  __shared__ float rsum[4];

  float s0 = scores[(size_t)tid*B_ + b];
  float s1 = scores[(size_t)(tid+256)*B_ + b];
  float mx = fmaxf(s0,s1);
  #pragma unroll
  for (int s=32;s>=1;s>>=1) mx = fmaxf(mx, __shfl_xor(mx, s, 64));
  if ((tid & 63)==0) rmax[tid>>6]=mx;
  __syncthreads();
  mx = fmaxf(fmaxf(rmax[0],rmax[1]), fmaxf(rmax[2],rmax[3]));
  float e0 = __expf(s0-mx), e1 = __expf(s1-mx);
  float sm = e0+e1;
  #pragma unroll
  for (int s=32;s>=1;s>>=1) sm += __shfl_xor(sm, s, 64);
  if ((tid & 63)==0) rsum[tid>>6]=sm;
  __syncthreads();
  sm = rsum[0]+rsum[1]+rsum[2]+rsum[3];
  float inv = 1.f/sm;
  wl[tid] = e0*inv; wl[tid+256] = e1*inv;
  __syncthreads();

  float2 acc = {0.f, 0.f};
  const int h0 = tid*2;
  #pragma unroll 4
  for (int t=0;t<T_;t++){
    float wt = wl[t];
    float2 hv = *(const float2*)(hs + ((size_t)t*B_ + b)*H_ + h0);
    acc.x += wt*hv.x; acc.y += wt*hv.y;
  }
  *(float2*)(out + (size_t)b*H_ + h0) = acc;
}

// ---------------------------------------------------------------------------
extern "C" void kernel_launch(void* const* d_in, const int* in_sizes, int n_in,
                              void* d_out, int out_size, void* d_ws, size_t ws_size,
                              hipStream_t stream)
{
  const float* x   = (const float*)d_in[0];
  const float* Wih = (const float*)d_in[1];
  const float* Whh = (const float*)d_in[2];
  const float* bih = (const float*)d_in[3];
  const float* bhh = (const float*)d_in[4];
  const float* aW  = (const float*)d_in[5];
  const float* ab  = (const float*)d_in[6];
  const float* av  = (const float*)d_in[7];
  float* out = (float*)d_out;

  char* ws = (char*)d_ws;
  float*    xproj = (float*)(ws + XPROJ_OFF);
  float*    hs    = (float*)(ws + HS_OFF);
  float*    sc    = (float*)(ws + SC_OFF);   // aliases xproj (dead after scan)
  unsigned* bar   = (unsigned*)d_out;        // 32 KB, fully overwritten by softmax_ctx

  zero_bar   <<<BAR_WORDS/256, 256, 0, stream>>>(bar);
  xproj_gemm <<<dim3(256,12),  256, 0, stream>>>(x, Wih, bih, xproj);
  scan_kernel<<<256,           256, 0, stream>>>(Whh, bhh, xproj, hs, bar);
  attn_scores<<<dim3(256),     256, 0, stream>>>(hs, aW, ab, av, sc);
  softmax_ctx<<<64,            256, 0, stream>>>(sc, hs, out);
}

// Round 8
// 4028.870 us; speedup vs baseline: 5.1905x; 1.3592x over previous
//
#include <hip/hip_runtime.h>

// Problem sizes (fixed by the reference)
#define T_  512
#define B_  64
#define I_  256
#define H_  512
#define G3_ 1536

// Workspace layout (bytes) — total EXACTLY 256 MB.
// scores reuses xproj's memory (xproj dead after scan_kernel).
// The 32 KB flag-barrier lives in d_out (dead until softmax_ctx rewrites it).
#define XPROJ_BYTES ((size_t)T_*B_*G3_*4)   // 201,326,592
#define HS_BYTES    ((size_t)T_*B_*H_*4)    //  67,108,864
#define XPROJ_OFF   ((size_t)0)
#define HS_OFF      (XPROJ_OFF + XPROJ_BYTES)
#define SC_OFF      ((size_t)0)             // alias: used only after scan

// Barrier: 8 groups x 32 WGs x 32-word (128 B) padded flag slots = 8192 words.
#define BAR_WORDS 8192

__device__ __forceinline__ float sigm_f(float x){
  x = fminf(fmaxf(x, -30.f), 30.f);
  return 1.f/(1.f + __expf(-x));
}
__device__ __forceinline__ float tanh_f(float x){
  x = fminf(fmaxf(x, -15.f), 15.f);
  float e = __expf(2.f*x);
  return (e-1.f)/(e+1.f);
}

// ---------------------------------------------------------------------------
// Kernel 0: zero the flag barrier (lives in d_out, re-poisoned each call)
// ---------------------------------------------------------------------------
__global__ void zero_bar(unsigned* __restrict__ bar){
  bar[blockIdx.x*256 + threadIdx.x] = 0u;
}

// ---------------------------------------------------------------------------
// Kernel 1: x_proj[t][b][g] = sum_i x[b][t][i]*Wih[g][i] + bih[g]
// M=32768 rows (r = t*64+b), N=1536, K=256. 128x128x32 tiles, 8x8 microtile.
// ---------------------------------------------------------------------------
__global__ __launch_bounds__(256, 2) void xproj_gemm(
    const float* __restrict__ x, const float* __restrict__ Wih,
    const float* __restrict__ bih, float* __restrict__ xproj)
{
  __shared__ __align__(16) float As[32][132];
  __shared__ __align__(16) float Bs[32][132];
  const int tid = threadIdx.x;
  const int tx = tid & 15, ty = tid >> 4;
  const int r0 = blockIdx.x * 128;
  const int n0 = blockIdx.y * 128;

  float acc[8][8];
  #pragma unroll
  for (int i=0;i<8;i++)
    #pragma unroll
    for (int j=0;j<8;j++) acc[i][j] = 0.f;

  for (int kt = 0; kt < I_; kt += 32) {
    #pragma unroll
    for (int p = 0; p < 4; p++) {
      int f4 = p*256 + tid;
      int m  = f4 >> 3;          // local row 0..127
      int kf = f4 & 7;           // k-float4 0..7
      int r  = r0 + m;
      // x[b][t][i], b=r&63, t=r>>6
      const float4 va = *(const float4*)(x + (((size_t)(r & 63))*T_ + (size_t)(r >> 6))*I_ + kt + kf*4);
      As[kf*4+0][m]=va.x; As[kf*4+1][m]=va.y; As[kf*4+2][m]=va.z; As[kf*4+3][m]=va.w;
      const float4 vb = *(const float4*)(Wih + ((size_t)(n0 + m))*I_ + kt + kf*4);
      Bs[kf*4+0][m]=vb.x; Bs[kf*4+1][m]=vb.y; Bs[kf*4+2][m]=vb.z; Bs[kf*4+3][m]=vb.w;
    }
    __syncthreads();
    #pragma unroll
    for (int kk=0;kk<32;kk++){
      float a[8], b[8];
      *(float4*)&a[0] = *(const float4*)&As[kk][ty*8];
      *(float4*)&a[4] = *(const float4*)&As[kk][ty*8+4];
      *(float4*)&b[0] = *(const float4*)&Bs[kk][tx*8];
      *(float4*)&b[4] = *(const float4*)&Bs[kk][tx*8+4];
      #pragma unroll
      for (int i=0;i<8;i++)
        #pragma unroll
        for (int j=0;j<8;j++)
          acc[i][j] += a[i]*b[j];
    }
    __syncthreads();
  }
  float bias[8];
  #pragma unroll
  for (int j=0;j<8;j++) bias[j] = bih[n0 + tx*8 + j];
  #pragma unroll
  for (int i=0;i<8;i++){
    float* o = xproj + ((size_t)(r0 + ty*8 + i))*G3_ + n0 + tx*8;
    float4 o0 = { acc[i][0]+bias[0], acc[i][1]+bias[1], acc[i][2]+bias[2], acc[i][3]+bias[3] };
    float4 o1 = { acc[i][4]+bias[4], acc[i][5]+bias[5], acc[i][6]+bias[6], acc[i][7]+bias[7] };
    *(float4*)o = o0; *(float4*)(o+4) = o1;
  }
}

// ---------------------------------------------------------------------------
// Kernel 2: persistent GRU scan.
// 256 WGs x 256 thr. group = bid&7 owns batches [8g,8g+8); WG w = bid>>3 owns
// gate-aligned j-slice [16w,16w+16). W_hh rows {j,512+j,1024+j} in VGPRs.
// h (8x512) in LDS. Sync v3 (validated R7): NO fences; h exchanged via
// agent-scope relaxed atomics (L1/L2-bypass to device coherence point);
// __syncthreads() drains vmcnt(0) before s_barrier, ordering data stores
// before the flag store; pollers' reloads are control-dependent on the flag.
// R8 changes (R7: 9.6us/step = 2.7 compute + ~6.9 sync/mem):
//  (a) reload reg-staged: 8 independent atomic loads -> regs, then ds_writes
//      (was load->ds_write pairs = 8 serialized coherence-point round trips)
//  (b) merging butterfly reduction: lane kq ends with batch kq&7 (24 shfls
//      instead of 96, static register indices only)
//  (c) epilogue parallel across 128 lanes (16 rows x 8 batches), 1 store each
// ---------------------------------------------------------------------------
__global__ __launch_bounds__(256, 1) void scan_kernel(
    const float* __restrict__ Whh, const float* __restrict__ bhh,
    const float* __restrict__ xproj, float* __restrict__ hs,
    unsigned* __restrict__ bar)
{
  __shared__ __align__(16) float hl[8*H_];   // 16 KB: h for the 8 batches
  const int tid = threadIdx.x;
  const int bid = blockIdx.x;
  const int grp = bid & 7;
  const int w   = bid >> 3;
  const int b0  = grp * 8;
  const int rg  = tid >> 4;      // 0..15
  const int kq  = tid & 15;      // 0..15
  const int j   = w*16 + rg;

  unsigned* flags  = bar + (size_t)grp*1024;   // 32 slots x 32 words (128 B)
  unsigned* flag_p = flags + (size_t)w*32;

  // zero h
  float4* hl4w = (float4*)hl;
  #pragma unroll
  for (int p=0;p<4;p++) hl4w[p*256+tid] = make_float4(0.f,0.f,0.f,0.f);

  // W_hh -> registers (float4 index kq + mq*16 covers k = 4kq + 64mq + c)
  float4 wr4[8], wz4[8], wn4[8];
  {
    const float4* pr = (const float4*)(Whh + (size_t)j*H_);
    const float4* pz = (const float4*)(Whh + (size_t)(H_+j)*H_);
    const float4* pn = (const float4*)(Whh + (size_t)(2*H_+j)*H_);
    #pragma unroll
    for (int mq=0;mq<8;mq++){ wr4[mq]=pr[kq+mq*16]; wz4[mq]=pz[kq+mq*16]; wn4[mq]=pn[kq+mq*16]; }
  }
  const float br = bhh[j], bz = bhh[H_+j], bn = bhh[2*H_+j];

  const bool q0 = (kq & 1) != 0, q1 = (kq & 2) != 0, q2 = (kq & 4) != 0;

  __syncthreads();

  const float4* hl4 = (const float4*)hl;

  for (int t=0; t<T_; t++){
    // prefetch x_proj gate inputs: lane kq<8 loads batch kq's 3 gate inputs
    float xr_ = 0.f, xz_ = 0.f, xn_ = 0.f;
    if (kq < 8){
      const float* xp = xproj + ((size_t)t*B_ + b0 + kq)*G3_ + j;
      xr_ = xp[0]; xz_ = xp[H_]; xn_ = xp[2*H_];
    }
    // dots: per-thread partials over 32 k-values for 8 batches x 3 gates
    float ar[8], az[8], an[8];
    #pragma unroll
    for (int b=0;b<8;b++){ ar[b]=0.f; az[b]=0.f; an[b]=0.f; }
    #pragma unroll
    for (int mq=0;mq<8;mq++){
      #pragma unroll
      for (int b=0;b<8;b++){
        const float4 hv = hl4[b*128 + kq + mq*16];   // 16 banks, 4-way bcast: conflict-free
        ar[b] += hv.x*wr4[mq].x + hv.y*wr4[mq].y + hv.z*wr4[mq].z + hv.w*wr4[mq].w;
        az[b] += hv.x*wz4[mq].x + hv.y*wz4[mq].y + hv.z*wz4[mq].z + hv.w*wz4[mq].w;
        an[b] += hv.x*wn4[mq].x + hv.y*wn4[mq].y + hv.z*wn4[mq].z + hv.w*wn4[mq].w;
      }
    }
    // merging butterfly over the 16 kq lanes: at each stage keep the batches
    // whose b-bit matches my lane bit, send the others. Lane kq ends holding
    // the full sum for batch b = kq&7 (duplicated in kq and kq+8).
    float s_r, s_z, s_n;
    {
      float kr[4], kz[4], kn[4];
      #pragma unroll
      for (int i=0;i<4;i++){
        float sr = q0 ? ar[2*i]   : ar[2*i+1];
        float tr = q0 ? ar[2*i+1] : ar[2*i];
        kr[i] = tr + __shfl_xor(sr, 1, 64);
        float sz = q0 ? az[2*i]   : az[2*i+1];
        float tz = q0 ? az[2*i+1] : az[2*i];
        kz[i] = tz + __shfl_xor(sz, 1, 64);
        float sn = q0 ? an[2*i]   : an[2*i+1];
        float tn = q0 ? an[2*i+1] : an[2*i];
        kn[i] = tn + __shfl_xor(sn, 1, 64);
      }
      float mr[2], mz[2], mn[2];
      #pragma unroll
      for (int i=0;i<2;i++){
        float sr = q1 ? kr[2*i]   : kr[2*i+1];
        float tr = q1 ? kr[2*i+1] : kr[2*i];
        mr[i] = tr + __shfl_xor(sr, 2, 64);
        float sz = q1 ? kz[2*i]   : kz[2*i+1];
        float tz = q1 ? kz[2*i+1] : kz[2*i];
        mz[i] = tz + __shfl_xor(sz, 2, 64);
        float sn = q1 ? kn[2*i]   : kn[2*i+1];
        float tn = q1 ? kn[2*i+1] : kn[2*i];
        mn[i] = tn + __shfl_xor(sn, 2, 64);
      }
      s_r = (q2 ? mr[1] : mr[0]) + __shfl_xor(q2 ? mr[0] : mr[1], 4, 64);
      s_z = (q2 ? mz[1] : mz[0]) + __shfl_xor(q2 ? mz[0] : mz[1], 4, 64);
      s_n = (q2 ? mn[1] : mn[0]) + __shfl_xor(q2 ? mn[0] : mn[1], 4, 64);
      s_r += __shfl_xor(s_r, 8, 64);
      s_z += __shfl_xor(s_z, 8, 64);
      s_n += __shfl_xor(s_n, 8, 64);
    }
    // gates + h_new: 128 lanes (rg x kq<8), one batch each, one store each.
    // Stores are agent-scope relaxed atomics (write-through, no L2 dirt).
    if (kq < 8){
      float rr = sigm_f(xr_ + s_r + br);
      float zz = sigm_f(xz_ + s_z + bz);
      float nn = tanh_f(xn_ + rr*(s_n + bn));
      float ho = hl[kq*H_ + j];
      __hip_atomic_store(hs + ((size_t)t*B_ + b0 + kq)*H_ + j,
                         (1.f-zz)*nn + zz*ho,
                         __ATOMIC_RELAXED, __HIP_MEMORY_SCOPE_AGENT);
    }
    if (t == T_-1) break;

    // ---- sync v3: no fences. syncthreads drains vmcnt(0) (data stores
    // complete), then flag store, parallel poll. ----
    __syncthreads();
    const unsigned gen = (unsigned)t + 1u;
    if (tid == 0)
      __hip_atomic_store(flag_p, gen, __ATOMIC_RELAXED, __HIP_MEMORY_SCOPE_AGENT);
    if (tid < 32){
      unsigned* fp = flags + (size_t)tid*32;
      while (__hip_atomic_load(fp, __ATOMIC_RELAXED, __HIP_MEMORY_SCOPE_AGENT) < gen)
        __builtin_amdgcn_s_sleep(1);
    }
    __syncthreads();

    // reload full h (8x512 = 2048 x 8B): reg-stage so the 8 bypass loads
    // pipeline (issue all, single drain) instead of 8 serialized round trips
    {
      unsigned long long* src = (unsigned long long*)(hs + ((size_t)t*B_ + b0)*H_);
      unsigned long long* dst = (unsigned long long*)hl;
      unsigned long long v[8];
      #pragma unroll
      for (int p=0;p<8;p++)
        v[p] = __hip_atomic_load(src + p*256 + tid,
                                 __ATOMIC_RELAXED, __HIP_MEMORY_SCOPE_AGENT);
      #pragma unroll
      for (int p=0;p<8;p++)
        dst[p*256+tid] = v[p];
    }
    __syncthreads();
  }
}

// ---------------------------------------------------------------------------
// Kernel 3: scores[r] = sum_h' v[h'] * tanh( sum_h hs[r][h]*aW[h'][h] + ab[h'] )
// M=32768 rows, N=512 (reduced, fused), K=512. 128-row tiles, 4 N-subtiles.
// ---------------------------------------------------------------------------
__global__ __launch_bounds__(256, 2) void attn_scores(
    const float* __restrict__ hs, const float* __restrict__ aW,
    const float* __restrict__ ab, const float* __restrict__ av,
    float* __restrict__ scores)
{
  __shared__ __align__(16) float As[32][132];
  __shared__ __align__(16) float Bs[32][132];
  const int tid = threadIdx.x;
  const int tx = tid & 15, ty = tid >> 4;
  const int r0 = blockIdx.x * 128;

  float sacc[8];
  #pragma unroll
  for (int i=0;i<8;i++) sacc[i]=0.f;

  for (int ntl=0; ntl<4; ntl++){
    const int n0 = ntl*128;
    float acc[8][8];
    #pragma unroll
    for (int i=0;i<8;i++)
      #pragma unroll
      for (int j2=0;j2<8;j2++) acc[i][j2]=0.f;

    for (int kt=0; kt<H_; kt+=32){
      #pragma unroll
      for (int p=0;p<4;p++){
        int f4 = p*256+tid; int m = f4>>3; int kf = f4&7;
        const float4 va = *(const float4*)(hs + ((size_t)(r0+m))*H_ + kt + kf*4);
        As[kf*4+0][m]=va.x; As[kf*4+1][m]=va.y; As[kf*4+2][m]=va.z; As[kf*4+3][m]=va.w;
        const float4 vb = *(const float4*)(aW + ((size_t)(n0+m))*H_ + kt + kf*4);
        Bs[kf*4+0][m]=vb.x; Bs[kf*4+1][m]=vb.y; Bs[kf*4+2][m]=vb.z; Bs[kf*4+3][m]=vb.w;
      }
      __syncthreads();
      #pragma unroll
      for (int kk=0;kk<32;kk++){
        float a[8], b[8];
        *(float4*)&a[0] = *(const float4*)&As[kk][ty*8];
        *(float4*)&a[4] = *(const float4*)&As[kk][ty*8+4];
        *(float4*)&b[0] = *(const float4*)&Bs[kk][tx*8];
        *(float4*)&b[4] = *(const float4*)&Bs[kk][tx*8+4];
        #pragma unroll
        for (int i=0;i<8;i++)
          #pragma unroll
          for (int j2=0;j2<8;j2++)
            acc[i][j2] += a[i]*b[j2];
      }
      __syncthreads();
    }
    float vv[8], bb2[8];
    #pragma unroll
    for (int j2=0;j2<8;j2++){ vv[j2]=av[n0+tx*8+j2]; bb2[j2]=ab[n0+tx*8+j2]; }
    #pragma unroll
    for (int i=0;i<8;i++){
      #pragma unroll
      for (int j2=0;j2<8;j2++){
        sacc[i] += tanh_f(acc[i][j2] + bb2[j2]) * vv[j2];
      }
    }
  }
  // reduce over tx (low 4 lane bits)
  #pragma unroll
  for (int i=0;i<8;i++){
    sacc[i] += __shfl_xor(sacc[i],1,64); sacc[i] += __shfl_xor(sacc[i],2,64);
    sacc[i] += __shfl_xor(sacc[i],4,64); sacc[i] += __shfl_xor(sacc[i],8,64);
  }
  if (tx == 0){
    #pragma unroll
    for (int i=0;i<8;i++) scores[r0 + ty*8 + i] = sacc[i];
  }
}

// ---------------------------------------------------------------------------
// Kernel 4: per-batch softmax over t, then context[b][h] = sum_t w[t]*hs[t][b][h]
// ---------------------------------------------------------------------------
__global__ __launch_bounds__(256, 2) void softmax_ctx(
    const float* __restrict__ scores, const float* __restrict__ hs,
    float* __restrict__ out)
{
  const int b = blockIdx.x;
  const int tid = threadIdx.x;
  __shared__ float wl[512];
  __shared__ float rmax[4];
  __shared__ float rsum[4];

  float s0 = scores[(size_t)tid*B_ + b];
  float s1 = scores[(size_t)(tid+256)*B_ + b];
  float mx = fmaxf(s0,s1);
  #pragma unroll
  for (int s=32;s>=1;s>>=1) mx = fmaxf(mx, __shfl_xor(mx, s, 64));
  if ((tid & 63)==0) rmax[tid>>6]=mx;
  __syncthreads();
  mx = fmaxf(fmaxf(rmax[0],rmax[1]), fmaxf(rmax[2],rmax[3]));
  float e0 = __expf(s0-mx), e1 = __expf(s1-mx);
  float sm = e0+e1;
  #pragma unroll
  for (int s=32;s>=1;s>>=1) sm += __shfl_xor(sm, s, 64);
  if ((tid & 63)==0) rsum[tid>>6]=sm;
  __syncthreads();
  sm = rsum[0]+rsum[1]+rsum[2]+rsum[3];
  float inv = 1.f/sm;
  wl[tid] = e0*inv; wl[tid+256] = e1*inv;
  __syncthreads();

  float2 acc = {0.f, 0.f};
  const int h0 = tid*2;
  #pragma unroll 4
  for (int t=0;t<T_;t++){
    float wt = wl[t];
    float2 hv = *(const float2*)(hs + ((size_t)t*B_ + b)*H_ + h0);
    acc.x += wt*hv.x; acc.y += wt*hv.y;
  }
  *(float2*)(out + (size_t)b*H_ + h0) = acc;
}

// ---------------------------------------------------------------------------
extern "C" void kernel_launch(void* const* d_in, const int* in_sizes, int n_in,
                              void* d_out, int out_size, void* d_ws, size_t ws_size,
                              hipStream_t stream)
{
  const float* x   = (const float*)d_in[0];
  const float* Wih = (const float*)d_in[1];
  const float* Whh = (const float*)d_in[2];
  const float* bih = (const float*)d_in[3];
  const float* bhh = (const float*)d_in[4];
  const float* aW  = (const float*)d_in[5];
  const float* ab  = (const float*)d_in[6];
  const float* av  = (const float*)d_in[7];
  float* out = (float*)d_out;

  char* ws = (char*)d_ws;
  float*    xproj = (float*)(ws + XPROJ_OFF);
  float*    hs    = (float*)(ws + HS_OFF);
  float*    sc    = (float*)(ws + SC_OFF);   // aliases xproj (dead after scan)
  unsigned* bar   = (unsigned*)d_out;        // 32 KB, fully overwritten by softmax_ctx

  zero_bar   <<<BAR_WORDS/256, 256, 0, stream>>>(bar);
  xproj_gemm <<<dim3(256,12),  256, 0, stream>>>(x, Wih, bih, xproj);
  scan_kernel<<<256,           256, 0, stream>>>(Whh, bhh, xproj, hs, bar);
  attn_scores<<<dim3(256),     256, 0, stream>>>(hs, aW, ab, av, sc);
  softmax_ctx<<<64,            256, 0, stream>>>(sc, hs, out);
}

// Round 9
// 3028.314 us; speedup vs baseline: 6.9055x; 1.3304x over previous
//
#include <hip/hip_runtime.h>

// Problem sizes (fixed by the reference)
#define T_  512
#define B_  64
#define I_  256
#define H_  512
#define G3_ 1536

// Workspace layout (bytes) — total EXACTLY 256 MB.
// scores reuses xproj's memory (xproj dead after scan_kernel).
// The 64 KB flag-barrier lives in d_out (dead until softmax_ctx rewrites it).
#define XPROJ_BYTES ((size_t)T_*B_*G3_*4)   // 201,326,592
#define HS_BYTES    ((size_t)T_*B_*H_*4)    //  67,108,864
#define XPROJ_OFF   ((size_t)0)
#define HS_OFF      (XPROJ_OFF + XPROJ_BYTES)
#define SC_OFF      ((size_t)0)             // alias: used only after scan

// Barrier: 8 groups x 2 streams x 32 WGs x 32-word (128 B) slots = 16384 words.
#define BAR_WORDS 16384

__device__ __forceinline__ float sigm_f(float x){
  x = fminf(fmaxf(x, -30.f), 30.f);
  return 1.f/(1.f + __expf(-x));
}
__device__ __forceinline__ float tanh_f(float x){
  x = fminf(fmaxf(x, -15.f), 15.f);
  float e = __expf(2.f*x);
  return (e-1.f)/(e+1.f);
}

// Merging butterfly over 16 kq lanes for 4 batch-partials: lane kq ends with
// the full sum of batch (kq&3) (duplicated across lane quads). Keep/send
// pattern validated in R8 (8-batch variant).
__device__ __forceinline__ float reduce4(float a0, float a1, float a2, float a3,
                                         bool q0, bool q1){
  float s0 = q0 ? a0 : a1;              // send
  float k0 = (q0 ? a1 : a0) + __shfl_xor(s0, 1, 64);
  float s1 = q0 ? a2 : a3;
  float k1 = (q0 ? a3 : a2) + __shfl_xor(s1, 1, 64);
  float sm = q1 ? k0 : k1;
  float m  = (q1 ? k1 : k0) + __shfl_xor(sm, 2, 64);
  m += __shfl_xor(m, 4, 64);
  m += __shfl_xor(m, 8, 64);
  return m;
}

// ---------------------------------------------------------------------------
// Kernel 0: zero the flag barrier (lives in d_out, re-poisoned each call)
// ---------------------------------------------------------------------------
__global__ void zero_bar(unsigned* __restrict__ bar){
  bar[blockIdx.x*256 + threadIdx.x] = 0u;
}

// ---------------------------------------------------------------------------
// Kernel 1: x_proj[t][b][g] = sum_i x[b][t][i]*Wih[g][i] + bih[g]
// M=32768 rows (r = t*64+b), N=1536, K=256. 128x128x32 tiles, 8x8 microtile.
// ---------------------------------------------------------------------------
__global__ __launch_bounds__(256, 2) void xproj_gemm(
    const float* __restrict__ x, const float* __restrict__ Wih,
    const float* __restrict__ bih, float* __restrict__ xproj)
{
  __shared__ __align__(16) float As[32][132];
  __shared__ __align__(16) float Bs[32][132];
  const int tid = threadIdx.x;
  const int tx = tid & 15, ty = tid >> 4;
  const int r0 = blockIdx.x * 128;
  const int n0 = blockIdx.y * 128;

  float acc[8][8];
  #pragma unroll
  for (int i=0;i<8;i++)
    #pragma unroll
    for (int j=0;j<8;j++) acc[i][j] = 0.f;

  for (int kt = 0; kt < I_; kt += 32) {
    #pragma unroll
    for (int p = 0; p < 4; p++) {
      int f4 = p*256 + tid;
      int m  = f4 >> 3;          // local row 0..127
      int kf = f4 & 7;           // k-float4 0..7
      int r  = r0 + m;
      // x[b][t][i], b=r&63, t=r>>6
      const float4 va = *(const float4*)(x + (((size_t)(r & 63))*T_ + (size_t)(r >> 6))*I_ + kt + kf*4);
      As[kf*4+0][m]=va.x; As[kf*4+1][m]=va.y; As[kf*4+2][m]=va.z; As[kf*4+3][m]=va.w;
      const float4 vb = *(const float4*)(Wih + ((size_t)(n0 + m))*I_ + kt + kf*4);
      Bs[kf*4+0][m]=vb.x; Bs[kf*4+1][m]=vb.y; Bs[kf*4+2][m]=vb.z; Bs[kf*4+3][m]=vb.w;
    }
    __syncthreads();
    #pragma unroll
    for (int kk=0;kk<32;kk++){
      float a[8], b[8];
      *(float4*)&a[0] = *(const float4*)&As[kk][ty*8];
      *(float4*)&a[4] = *(const float4*)&As[kk][ty*8+4];
      *(float4*)&b[0] = *(const float4*)&Bs[kk][tx*8];
      *(float4*)&b[4] = *(const float4*)&Bs[kk][tx*8+4];
      #pragma unroll
      for (int i=0;i<8;i++)
        #pragma unroll
        for (int j=0;j<8;j++)
          acc[i][j] += a[i]*b[j];
    }
    __syncthreads();
  }
  float bias[8];
  #pragma unroll
  for (int j=0;j<8;j++) bias[j] = bih[n0 + tx*8 + j];
  #pragma unroll
  for (int i=0;i<8;i++){
    float* o = xproj + ((size_t)(r0 + ty*8 + i))*G3_ + n0 + tx*8;
    float4 o0 = { acc[i][0]+bias[0], acc[i][1]+bias[1], acc[i][2]+bias[2], acc[i][3]+bias[3] };
    float4 o1 = { acc[i][4]+bias[4], acc[i][5]+bias[5], acc[i][6]+bias[6], acc[i][7]+bias[7] };
    *(float4*)o = o0; *(float4*)(o+4) = o1;
  }
}

// ---------------------------------------------------------------------------
// Kernel 2: persistent GRU scan, 2-stream software pipeline (R9).
// 256 WGs x 256 thr. group = bid&7 owns batches [8g,8g+8); WG w = bid>>3 owns
// j-slice [16w,16w+16). W_hh rows in VGPRs. Sync v3 (validated R7/R8): no
// fences; h + flags via agent-scope relaxed atomics (bypass to coherence
// point); __syncthreads() drains vmcnt(0) before s_barrier => stores are
// visible before the flag store; consumers' loads are control-dependent.
// R9: batches split into streams A (b0..b0+3, hlA) and B (b0+4.., hlB):
//   compA -> flagA -> compB -> flagB -> pollA -> loadA -> pollB -> loadB
// A's store+flag latency hides under compB; loadA's latency hides under
// pollB. xproj gate inputs for t+1 prefetched at end of step t.
// ---------------------------------------------------------------------------
__global__ __launch_bounds__(256, 1) void scan_kernel(
    const float* __restrict__ Whh, const float* __restrict__ bhh,
    const float* __restrict__ xproj, float* __restrict__ hs,
    unsigned* __restrict__ bar)
{
  __shared__ __align__(16) float hlA[4*H_];   // 8 KB: stream A h (4 batches)
  __shared__ __align__(16) float hlB[4*H_];   // 8 KB: stream B h
  const int tid = threadIdx.x;
  const int bid = blockIdx.x;
  const int grp = bid & 7;
  const int w   = bid >> 3;
  const int b0  = grp * 8;
  const int rg  = tid >> 4;      // 0..15
  const int kq  = tid & 15;      // 0..15
  const int j   = w*16 + rg;

  unsigned* gflags  = bar + (size_t)grp*2048;   // per group: 2 x 32 slots
  unsigned* flagsA  = gflags;
  unsigned* flagsB  = gflags + 1024;
  unsigned* flagA_p = flagsA + (size_t)w*32;
  unsigned* flagB_p = flagsB + (size_t)w*32;

  // zero both h buffers
  { float4* a4 = (float4*)hlA; float4* b4 = (float4*)hlB;
    #pragma unroll
    for (int p=0;p<2;p++){
      a4[p*256+tid] = make_float4(0.f,0.f,0.f,0.f);
      b4[p*256+tid] = make_float4(0.f,0.f,0.f,0.f);
    } }

  // W_hh -> registers (float4 index kq + mq*16 covers k = 4kq + 64mq + c)
  float4 wr4[8], wz4[8], wn4[8];
  {
    const float4* pr = (const float4*)(Whh + (size_t)j*H_);
    const float4* pz = (const float4*)(Whh + (size_t)(H_+j)*H_);
    const float4* pn = (const float4*)(Whh + (size_t)(2*H_+j)*H_);
    #pragma unroll
    for (int mq=0;mq<8;mq++){ wr4[mq]=pr[kq+mq*16]; wz4[mq]=pz[kq+mq*16]; wn4[mq]=pn[kq+mq*16]; }
  }
  const float br = bhh[j], bz = bhh[H_+j], bn = bhh[2*H_+j];
  const bool q0 = (kq & 1) != 0, q1 = (kq & 2) != 0;

  __syncthreads();

  const float4* hA4 = (const float4*)hlA;
  const float4* hB4 = (const float4*)hlB;

  // xproj prefetch for t=0: lane kq<8 holds batch (b0+kq)'s 3 gate inputs
  // (kq<4 => stream A, kq 4..7 => stream B)
  float xr_ = 0.f, xz_ = 0.f, xn_ = 0.f;
  if (kq < 8){
    const float* xp = xproj + ((size_t)(b0 + kq))*G3_ + j;
    xr_ = xp[0]; xz_ = xp[H_]; xn_ = xp[2*H_];
  }

  for (int t=0; t<T_; t++){
    const unsigned gen = (unsigned)t + 1u;

    // ================= phase A: stream A step =================
    {
      float ar[4]={0.f,0.f,0.f,0.f}, az[4]={0.f,0.f,0.f,0.f}, an[4]={0.f,0.f,0.f,0.f};
      #pragma unroll
      for (int mq=0;mq<8;mq++){
        #pragma unroll
        for (int b=0;b<4;b++){
          const float4 hv = hA4[b*128 + kq + mq*16];
          ar[b] += hv.x*wr4[mq].x + hv.y*wr4[mq].y + hv.z*wr4[mq].z + hv.w*wr4[mq].w;
          az[b] += hv.x*wz4[mq].x + hv.y*wz4[mq].y + hv.z*wz4[mq].z + hv.w*wz4[mq].w;
          an[b] += hv.x*wn4[mq].x + hv.y*wn4[mq].y + hv.z*wn4[mq].z + hv.w*wn4[mq].w;
        }
      }
      float sr = reduce4(ar[0],ar[1],ar[2],ar[3],q0,q1);
      float sz = reduce4(az[0],az[1],az[2],az[3],q0,q1);
      float sn = reduce4(an[0],an[1],an[2],an[3],q0,q1);
      if (kq < 4){     // lane holds batch kq of stream A
        float rr = sigm_f(xr_ + sr + br);
        float zz = sigm_f(xz_ + sz + bz);
        float nn = tanh_f(xn_ + rr*(sn + bn));
        float ho = hlA[kq*H_ + j];
        __hip_atomic_store(hs + ((size_t)t*B_ + b0 + kq)*H_ + j,
                           (1.f-zz)*nn + zz*ho,
                           __ATOMIC_RELAXED, __HIP_MEMORY_SCOPE_AGENT);
      }
    }
    __syncthreads();   // S1: all waves' A-stores drained (vmcnt0 before barrier)
    if (tid == 0)
      __hip_atomic_store(flagA_p, gen, __ATOMIC_RELAXED, __HIP_MEMORY_SCOPE_AGENT);

    // ================= phase B: stream B step (hides A's store latency) ====
    {
      float ar[4]={0.f,0.f,0.f,0.f}, az[4]={0.f,0.f,0.f,0.f}, an[4]={0.f,0.f,0.f,0.f};
      #pragma unroll
      for (int mq=0;mq<8;mq++){
        #pragma unroll
        for (int b=0;b<4;b++){
          const float4 hv = hB4[b*128 + kq + mq*16];
          ar[b] += hv.x*wr4[mq].x + hv.y*wr4[mq].y + hv.z*wr4[mq].z + hv.w*wr4[mq].w;
          az[b] += hv.x*wz4[mq].x + hv.y*wz4[mq].y + hv.z*wz4[mq].z + hv.w*wz4[mq].w;
          an[b] += hv.x*wn4[mq].x + hv.y*wn4[mq].y + hv.z*wn4[mq].z + hv.w*wn4[mq].w;
        }
      }
      float sr = reduce4(ar[0],ar[1],ar[2],ar[3],q0,q1);
      float sz = reduce4(az[0],az[1],az[2],az[3],q0,q1);
      float sn = reduce4(an[0],an[1],an[2],an[3],q0,q1);
      if (kq >= 4 && kq < 8){   // lane holds batch (kq&3) of stream B = b0+kq
        float rr = sigm_f(xr_ + sr + br);
        float zz = sigm_f(xz_ + sz + bz);
        float nn = tanh_f(xn_ + rr*(sn + bn));
        float ho = hlB[(kq-4)*H_ + j];
        __hip_atomic_store(hs + ((size_t)t*B_ + b0 + kq)*H_ + j,
                           (1.f-zz)*nn + zz*ho,
                           __ATOMIC_RELAXED, __HIP_MEMORY_SCOPE_AGENT);
      }
    }
    __syncthreads();   // S2
    if (tid == 0)
      __hip_atomic_store(flagB_p, gen, __ATOMIC_RELAXED, __HIP_MEMORY_SCOPE_AGENT);

    if (t == T_-1) break;

    // ============ detect + reload, pipelined across streams ============
    if (tid < 32){
      unsigned* fp = flagsA + (size_t)tid*32;
      while (__hip_atomic_load(fp, __ATOMIC_RELAXED, __HIP_MEMORY_SCOPE_AGENT) < gen)
        __builtin_amdgcn_s_sleep(1);
    }
    __syncthreads();   // S3: h_A[t+1] globally visible
    unsigned long long vA[4];
    {
      unsigned long long* srcA = (unsigned long long*)(hs + ((size_t)t*B_ + b0)*H_);
      #pragma unroll
      for (int p=0;p<4;p++)
        vA[p] = __hip_atomic_load(srcA + p*256 + tid,
                                  __ATOMIC_RELAXED, __HIP_MEMORY_SCOPE_AGENT);
    }
    if (tid < 32){     // loadA latency hides under this poll
      unsigned* fp = flagsB + (size_t)tid*32;
      while (__hip_atomic_load(fp, __ATOMIC_RELAXED, __HIP_MEMORY_SCOPE_AGENT) < gen)
        __builtin_amdgcn_s_sleep(1);
    }
    __syncthreads();   // S4: h_B[t+1] globally visible
    unsigned long long vB[4];
    {
      unsigned long long* srcB = (unsigned long long*)(hs + ((size_t)t*B_ + b0 + 4)*H_);
      #pragma unroll
      for (int p=0;p<4;p++)
        vB[p] = __hip_atomic_load(srcB + p*256 + tid,
                                  __ATOMIC_RELAXED, __HIP_MEMORY_SCOPE_AGENT);
    }
    {
      unsigned long long* dA = (unsigned long long*)hlA;
      #pragma unroll
      for (int p=0;p<4;p++) dA[p*256+tid] = vA[p];   // waits vA only (counted vmcnt)
      unsigned long long* dB = (unsigned long long*)hlB;
      #pragma unroll
      for (int p=0;p<4;p++) dB[p*256+tid] = vB[p];
    }
    // prefetch xproj gate inputs for step t+1 (consumed ~1.5us later)
    if (kq < 8){
      const float* xp = xproj + ((size_t)(t+1)*B_ + b0 + kq)*G3_ + j;
      xr_ = xp[0]; xz_ = xp[H_]; xn_ = xp[2*H_];
    }
    __syncthreads();   // S5: LDS h buffers ready for next step
  }
}

// ---------------------------------------------------------------------------
// Kernel 3: scores[r] = sum_h' v[h'] * tanh( sum_h hs[r][h]*aW[h'][h] + ab[h'] )
// M=32768 rows, N=512 (reduced, fused), K=512. 128-row tiles, 4 N-subtiles.
// ---------------------------------------------------------------------------
__global__ __launch_bounds__(256, 2) void attn_scores(
    const float* __restrict__ hs, const float* __restrict__ aW,
    const float* __restrict__ ab, const float* __restrict__ av,
    float* __restrict__ scores)
{
  __shared__ __align__(16) float As[32][132];
  __shared__ __align__(16) float Bs[32][132];
  const int tid = threadIdx.x;
  const int tx = tid & 15, ty = tid >> 4;
  const int r0 = blockIdx.x * 128;

  float sacc[8];
  #pragma unroll
  for (int i=0;i<8;i++) sacc[i]=0.f;

  for (int ntl=0; ntl<4; ntl++){
    const int n0 = ntl*128;
    float acc[8][8];
    #pragma unroll
    for (int i=0;i<8;i++)
      #pragma unroll
      for (int j2=0;j2<8;j2++) acc[i][j2]=0.f;

    for (int kt=0; kt<H_; kt+=32){
      #pragma unroll
      for (int p=0;p<4;p++){
        int f4 = p*256+tid; int m = f4>>3; int kf = f4&7;
        const float4 va = *(const float4*)(hs + ((size_t)(r0+m))*H_ + kt + kf*4);
        As[kf*4+0][m]=va.x; As[kf*4+1][m]=va.y; As[kf*4+2][m]=va.z; As[kf*4+3][m]=va.w;
        const float4 vb = *(const float4*)(aW + ((size_t)(n0+m))*H_ + kt + kf*4);
        Bs[kf*4+0][m]=vb.x; Bs[kf*4+1][m]=vb.y; Bs[kf*4+2][m]=vb.z; Bs[kf*4+3][m]=vb.w;
      }
      __syncthreads();
      #pragma unroll
      for (int kk=0;kk<32;kk++){
        float a[8], b[8];
        *(float4*)&a[0] = *(const float4*)&As[kk][ty*8];
        *(float4*)&a[4] = *(const float4*)&As[kk][ty*8+4];
        *(float4*)&b[0] = *(const float4*)&Bs[kk][tx*8];
        *(float4*)&b[4] = *(const float4*)&Bs[kk][tx*8+4];
        #pragma unroll
        for (int i=0;i<8;i++)
          #pragma unroll
          for (int j2=0;j2<8;j2++)
            acc[i][j2] += a[i]*b[j2];
      }
      __syncthreads();
    }
    float vv[8], bb2[8];
    #pragma unroll
    for (int j2=0;j2<8;j2++){ vv[j2]=av[n0+tx*8+j2]; bb2[j2]=ab[n0+tx*8+j2]; }
    #pragma unroll
    for (int i=0;i<8;i++){
      #pragma unroll
      for (int j2=0;j2<8;j2++){
        sacc[i] += tanh_f(acc[i][j2] + bb2[j2]) * vv[j2];
      }
    }
  }
  // reduce over tx (low 4 lane bits)
  #pragma unroll
  for (int i=0;i<8;i++){
    sacc[i] += __shfl_xor(sacc[i],1,64); sacc[i] += __shfl_xor(sacc[i],2,64);
    sacc[i] += __shfl_xor(sacc[i],4,64); sacc[i] += __shfl_xor(sacc[i],8,64);
  }
  if (tx == 0){
    #pragma unroll
    for (int i=0;i<8;i++) scores[r0 + ty*8 + i] = sacc[i];
  }
}

// ---------------------------------------------------------------------------
// Kernel 4: per-batch softmax over t, then context[b][h] = sum_t w[t]*hs[t][b][h]
// ---------------------------------------------------------------------------
__global__ __launch_bounds__(256, 2) void softmax_ctx(
    const float* __restrict__ scores, const float* __restrict__ hs,
    float* __restrict__ out)
{
  const int b = blockIdx.x;
  const int tid = threadIdx.x;
  __shared__ float wl[512];
  __shared__ float rmax[4];
  __shared__ float rsum[4];

  float s0 = scores[(size_t)tid*B_ + b];
  float s1 = scores[(size_t)(tid+256)*B_ + b];
  float mx = fmaxf(s0,s1);
  #pragma unroll
  for (int s=32;s>=1;s>>=1) mx = fmaxf(mx, __shfl_xor(mx, s, 64));
  if ((tid & 63)==0) rmax[tid>>6]=mx;
  __syncthreads();
  mx = fmaxf(fmaxf(rmax[0],rmax[1]), fmaxf(rmax[2],rmax[3]));
  float e0 = __expf(s0-mx), e1 = __expf(s1-mx);
  float sm = e0+e1;
  #pragma unroll
  for (int s=32;s>=1;s>>=1) sm += __shfl_xor(sm, s, 64);
  if ((tid & 63)==0) rsum[tid>>6]=sm;
  __syncthreads();
  sm = rsum[0]+rsum[1]+rsum[2]+rsum[3];
  float inv = 1.f/sm;
  wl[tid] = e0*inv; wl[tid+256] = e1*inv;
  __syncthreads();

  float2 acc = {0.f, 0.f};
  const int h0 = tid*2;
  #pragma unroll 4
  for (int t=0;t<T_;t++){
    float wt = wl[t];
    float2 hv = *(const float2*)(hs + ((size_t)t*B_ + b)*H_ + h0);
    acc.x += wt*hv.x; acc.y += wt*hv.y;
  }
  *(float2*)(out + (size_t)b*H_ + h0) = acc;
}

// ---------------------------------------------------------------------------
extern "C" void kernel_launch(void* const* d_in, const int* in_sizes, int n_in,
                              void* d_out, int out_size, void* d_ws, size_t ws_size,
                              hipStream_t stream)
{
  const float* x   = (const float*)d_in[0];
  const float* Wih = (const float*)d_in[1];
  const float* Whh = (const float*)d_in[2];
  const float* bih = (const float*)d_in[3];
  const float* bhh = (const float*)d_in[4];
  const float* aW  = (const float*)d_in[5];
  const float* ab  = (const float*)d_in[6];
  const float* av  = (const float*)d_in[7];
  float* out = (float*)d_out;

  char* ws = (char*)d_ws;
  float*    xproj = (float*)(ws + XPROJ_OFF);
  float*    hs    = (float*)(ws + HS_OFF);
  float*    sc    = (float*)(ws + SC_OFF);   // aliases xproj (dead after scan)
  unsigned* bar   = (unsigned*)d_out;        // 64 KB, fully overwritten by softmax_ctx

  zero_bar   <<<BAR_WORDS/256, 256, 0, stream>>>(bar);
  xproj_gemm <<<dim3(256,12),  256, 0, stream>>>(x, Wih, bih, xproj);
  scan_kernel<<<256,           256, 0, stream>>>(Whh, bhh, xproj, hs, bar);
  attn_scores<<<dim3(256),     256, 0, stream>>>(hs, aW, ab, av, sc);
  softmax_ctx<<<64,            256, 0, stream>>>(sc, hs, out);
}

// Round 10
// 2998.950 us; speedup vs baseline: 6.9731x; 1.0098x over previous
//
#include <hip/hip_runtime.h>

// Problem sizes (fixed by the reference)
#define T_  512
#define B_  64
#define I_  256
#define H_  512
#define G3_ 1536

// Workspace layout (bytes) — total EXACTLY 256 MB.
// scores reuses xproj's memory (xproj dead after scan_kernel).
// The 64 KB flag-barrier lives in d_out (dead until softmax_ctx rewrites it).
#define XPROJ_BYTES ((size_t)T_*B_*G3_*4)   // 201,326,592
#define HS_BYTES    ((size_t)T_*B_*H_*4)    //  67,108,864
#define XPROJ_OFF   ((size_t)0)
#define HS_OFF      (XPROJ_OFF + XPROJ_BYTES)
#define SC_OFF      ((size_t)0)             // alias: used only after scan

// Barrier: 8 groups x 2 streams x 32 WGs x 32-word (128 B) slots = 16384 words.
#define BAR_WORDS 16384

__device__ __forceinline__ float sigm_f(float x){
  x = fminf(fmaxf(x, -30.f), 30.f);
  return 1.f/(1.f + __expf(-x));
}
__device__ __forceinline__ float tanh_f(float x){
  x = fminf(fmaxf(x, -15.f), 15.f);
  float e = __expf(2.f*x);
  return (e-1.f)/(e+1.f);
}

// Merging butterfly over 16 kq lanes for 4 batch-partials: lane kq ends with
// the full sum of batch (kq&3) (duplicated across lane quads). Validated R9.
__device__ __forceinline__ float reduce4(float a0, float a1, float a2, float a3,
                                         bool q0, bool q1){
  float s0 = q0 ? a0 : a1;              // send
  float k0 = (q0 ? a1 : a0) + __shfl_xor(s0, 1, 64);
  float s1 = q0 ? a2 : a3;
  float k1 = (q0 ? a3 : a2) + __shfl_xor(s1, 1, 64);
  float sm = q1 ? k0 : k1;
  float m  = (q1 ? k1 : k0) + __shfl_xor(sm, 2, 64);
  m += __shfl_xor(m, 4, 64);
  m += __shfl_xor(m, 8, 64);
  return m;
}

// ---------------------------------------------------------------------------
// Kernel 0: zero the flag barrier (lives in d_out, re-poisoned each call)
// ---------------------------------------------------------------------------
__global__ void zero_bar(unsigned* __restrict__ bar){
  bar[blockIdx.x*256 + threadIdx.x] = 0u;
}

// ---------------------------------------------------------------------------
// Kernel 1: x_proj[t][b][g] = sum_i x[b][t][i]*Wih[g][i] + bih[g]
// M=32768 rows (r = t*64+b), N=1536, K=256. 128x128x32 tiles, 8x8 microtile.
// ---------------------------------------------------------------------------
__global__ __launch_bounds__(256, 2) void xproj_gemm(
    const float* __restrict__ x, const float* __restrict__ Wih,
    const float* __restrict__ bih, float* __restrict__ xproj)
{
  __shared__ __align__(16) float As[32][132];
  __shared__ __align__(16) float Bs[32][132];
  const int tid = threadIdx.x;
  const int tx = tid & 15, ty = tid >> 4;
  const int r0 = blockIdx.x * 128;
  const int n0 = blockIdx.y * 128;

  float acc[8][8];
  #pragma unroll
  for (int i=0;i<8;i++)
    #pragma unroll
    for (int j=0;j<8;j++) acc[i][j] = 0.f;

  for (int kt = 0; kt < I_; kt += 32) {
    #pragma unroll
    for (int p = 0; p < 4; p++) {
      int f4 = p*256 + tid;
      int m  = f4 >> 3;          // local row 0..127
      int kf = f4 & 7;           // k-float4 0..7
      int r  = r0 + m;
      // x[b][t][i], b=r&63, t=r>>6
      const float4 va = *(const float4*)(x + (((size_t)(r & 63))*T_ + (size_t)(r >> 6))*I_ + kt + kf*4);
      As[kf*4+0][m]=va.x; As[kf*4+1][m]=va.y; As[kf*4+2][m]=va.z; As[kf*4+3][m]=va.w;
      const float4 vb = *(const float4*)(Wih + ((size_t)(n0 + m))*I_ + kt + kf*4);
      Bs[kf*4+0][m]=vb.x; Bs[kf*4+1][m]=vb.y; Bs[kf*4+2][m]=vb.z; Bs[kf*4+3][m]=vb.w;
    }
    __syncthreads();
    #pragma unroll
    for (int kk=0;kk<32;kk++){
      float a[8], b[8];
      *(float4*)&a[0] = *(const float4*)&As[kk][ty*8];
      *(float4*)&a[4] = *(const float4*)&As[kk][ty*8+4];
      *(float4*)&b[0] = *(const float4*)&Bs[kk][tx*8];
      *(float4*)&b[4] = *(const float4*)&Bs[kk][tx*8+4];
      #pragma unroll
      for (int i=0;i<8;i++)
        #pragma unroll
        for (int j=0;j<8;j++)
          acc[i][j] += a[i]*b[j];
    }
    __syncthreads();
  }
  float bias[8];
  #pragma unroll
  for (int j=0;j<8;j++) bias[j] = bih[n0 + tx*8 + j];
  #pragma unroll
  for (int i=0;i<8;i++){
    float* o = xproj + ((size_t)(r0 + ty*8 + i))*G3_ + n0 + tx*8;
    float4 o0 = { acc[i][0]+bias[0], acc[i][1]+bias[1], acc[i][2]+bias[2], acc[i][3]+bias[3] };
    float4 o1 = { acc[i][4]+bias[4], acc[i][5]+bias[5], acc[i][6]+bias[6], acc[i][7]+bias[7] };
    *(float4*)o = o0; *(float4*)(o+4) = o1;
  }
}

// ---------------------------------------------------------------------------
// Kernel 2: persistent GRU scan, 2-stream software pipeline (R9, validated).
// Sync v3: no fences; h + flags via agent-scope relaxed atomics (bypass to
// coherence point); __syncthreads() drains vmcnt(0) before s_barrier =>
// stores visible before flag store; loads are control-dependent on flags.
// R10 tail shortening (R9: ~2.8us/step still in the serialized sync tail):
//  (a) single combined poll: lanes 0-31 watch A-flags, 32-63 watch B-flags
//      (one detect round + one barrier instead of two of each)
//  (b) xproj[t+1] prefetch issued BEFORE the poll (latency hides under spin)
//  (c) loadA+loadB issued back-to-back after one barrier (one RTT, pipelined)
// ---------------------------------------------------------------------------
__global__ __launch_bounds__(256, 1) void scan_kernel(
    const float* __restrict__ Whh, const float* __restrict__ bhh,
    const float* __restrict__ xproj, float* __restrict__ hs,
    unsigned* __restrict__ bar)
{
  __shared__ __align__(16) float hlA[4*H_];   // 8 KB: stream A h (4 batches)
  __shared__ __align__(16) float hlB[4*H_];   // 8 KB: stream B h
  const int tid = threadIdx.x;
  const int bid = blockIdx.x;
  const int grp = bid & 7;
  const int w   = bid >> 3;
  const int b0  = grp * 8;
  const int rg  = tid >> 4;      // 0..15
  const int kq  = tid & 15;      // 0..15
  const int j   = w*16 + rg;

  unsigned* gflags  = bar + (size_t)grp*2048;   // per group: 2 x 32 slots
  unsigned* flagsA  = gflags;
  unsigned* flagsB  = gflags + 1024;
  unsigned* flagA_p = flagsA + (size_t)w*32;
  unsigned* flagB_p = flagsB + (size_t)w*32;

  // zero both h buffers
  { float4* a4 = (float4*)hlA; float4* b4 = (float4*)hlB;
    #pragma unroll
    for (int p=0;p<2;p++){
      a4[p*256+tid] = make_float4(0.f,0.f,0.f,0.f);
      b4[p*256+tid] = make_float4(0.f,0.f,0.f,0.f);
    } }

  // W_hh -> registers (float4 index kq + mq*16 covers k = 4kq + 64mq + c)
  float4 wr4[8], wz4[8], wn4[8];
  {
    const float4* pr = (const float4*)(Whh + (size_t)j*H_);
    const float4* pz = (const float4*)(Whh + (size_t)(H_+j)*H_);
    const float4* pn = (const float4*)(Whh + (size_t)(2*H_+j)*H_);
    #pragma unroll
    for (int mq=0;mq<8;mq++){ wr4[mq]=pr[kq+mq*16]; wz4[mq]=pz[kq+mq*16]; wn4[mq]=pn[kq+mq*16]; }
  }
  const float br = bhh[j], bz = bhh[H_+j], bn = bhh[2*H_+j];
  const bool q0 = (kq & 1) != 0, q1 = (kq & 2) != 0;

  __syncthreads();

  const float4* hA4 = (const float4*)hlA;
  const float4* hB4 = (const float4*)hlB;

  // xproj prefetch for t=0: lane kq<8 holds batch (b0+kq)'s 3 gate inputs
  float xr_ = 0.f, xz_ = 0.f, xn_ = 0.f;
  if (kq < 8){
    const float* xp = xproj + ((size_t)(b0 + kq))*G3_ + j;
    xr_ = xp[0]; xz_ = xp[H_]; xn_ = xp[2*H_];
  }

  for (int t=0; t<T_; t++){
    const unsigned gen = (unsigned)t + 1u;

    // ================= phase A: stream A step =================
    {
      float ar[4]={0.f,0.f,0.f,0.f}, az[4]={0.f,0.f,0.f,0.f}, an[4]={0.f,0.f,0.f,0.f};
      #pragma unroll
      for (int mq=0;mq<8;mq++){
        #pragma unroll
        for (int b=0;b<4;b++){
          const float4 hv = hA4[b*128 + kq + mq*16];
          ar[b] += hv.x*wr4[mq].x + hv.y*wr4[mq].y + hv.z*wr4[mq].z + hv.w*wr4[mq].w;
          az[b] += hv.x*wz4[mq].x + hv.y*wz4[mq].y + hv.z*wz4[mq].z + hv.w*wz4[mq].w;
          an[b] += hv.x*wn4[mq].x + hv.y*wn4[mq].y + hv.z*wn4[mq].z + hv.w*wn4[mq].w;
        }
      }
      float sr = reduce4(ar[0],ar[1],ar[2],ar[3],q0,q1);
      float sz = reduce4(az[0],az[1],az[2],az[3],q0,q1);
      float sn = reduce4(an[0],an[1],an[2],an[3],q0,q1);
      if (kq < 4){     // lane holds batch kq of stream A
        float rr = sigm_f(xr_ + sr + br);
        float zz = sigm_f(xz_ + sz + bz);
        float nn = tanh_f(xn_ + rr*(sn + bn));
        float ho = hlA[kq*H_ + j];
        __hip_atomic_store(hs + ((size_t)t*B_ + b0 + kq)*H_ + j,
                           (1.f-zz)*nn + zz*ho,
                           __ATOMIC_RELAXED, __HIP_MEMORY_SCOPE_AGENT);
      }
    }
    __syncthreads();   // S1: all waves' A-stores drained (vmcnt0 before barrier)
    if (tid == 0)
      __hip_atomic_store(flagA_p, gen, __ATOMIC_RELAXED, __HIP_MEMORY_SCOPE_AGENT);

    // ================= phase B: stream B step (hides A's store latency) ====
    {
      float ar[4]={0.f,0.f,0.f,0.f}, az[4]={0.f,0.f,0.f,0.f}, an[4]={0.f,0.f,0.f,0.f};
      #pragma unroll
      for (int mq=0;mq<8;mq++){
        #pragma unroll
        for (int b=0;b<4;b++){
          const float4 hv = hB4[b*128 + kq + mq*16];
          ar[b] += hv.x*wr4[mq].x + hv.y*wr4[mq].y + hv.z*wr4[mq].z + hv.w*wr4[mq].w;
          az[b] += hv.x*wz4[mq].x + hv.y*wz4[mq].y + hv.z*wz4[mq].z + hv.w*wz4[mq].w;
          an[b] += hv.x*wn4[mq].x + hv.y*wn4[mq].y + hv.z*wn4[mq].z + hv.w*wn4[mq].w;
        }
      }
      float sr = reduce4(ar[0],ar[1],ar[2],ar[3],q0,q1);
      float sz = reduce4(az[0],az[1],az[2],az[3],q0,q1);
      float sn = reduce4(an[0],an[1],an[2],an[3],q0,q1);
      if (kq >= 4 && kq < 8){   // lane holds batch (kq&3) of stream B = b0+kq
        float rr = sigm_f(xr_ + sr + br);
        float zz = sigm_f(xz_ + sz + bz);
        float nn = tanh_f(xn_ + rr*(sn + bn));
        float ho = hlB[(kq-4)*H_ + j];
        __hip_atomic_store(hs + ((size_t)t*B_ + b0 + kq)*H_ + j,
                           (1.f-zz)*nn + zz*ho,
                           __ATOMIC_RELAXED, __HIP_MEMORY_SCOPE_AGENT);
      }
    }
    __syncthreads();   // S2: B-stores drained
    if (tid == 0)
      __hip_atomic_store(flagB_p, gen, __ATOMIC_RELAXED, __HIP_MEMORY_SCOPE_AGENT);

    if (t == T_-1) break;

    // prefetch xproj gate inputs for t+1 NOW — cached loads whose latency
    // hides under the poll spin below (R10-b)
    if (kq < 8){
      const float* xp = xproj + ((size_t)(t+1)*B_ + b0 + kq)*G3_ + j;
      xr_ = xp[0]; xz_ = xp[H_]; xn_ = xp[2*H_];
    }

    // combined dual-stream poll (R10-a): lanes 0-31 watch A, 32-63 watch B
    if (tid < 64){
      unsigned* fp = (tid < 32) ? (flagsA + (size_t)tid*32)
                                : (flagsB + (size_t)(tid-32)*32);
      while (__hip_atomic_load(fp, __ATOMIC_RELAXED, __HIP_MEMORY_SCOPE_AGENT) < gen)
        __builtin_amdgcn_s_sleep(1);
    }
    __syncthreads();   // S3: h_A[t+1] AND h_B[t+1] globally visible

    // issue both reloads back-to-back (one pipelined RTT), then LDS writes
    unsigned long long vA[4], vB[4];
    {
      unsigned long long* srcA = (unsigned long long*)(hs + ((size_t)t*B_ + b0)*H_);
      unsigned long long* srcB = (unsigned long long*)(hs + ((size_t)t*B_ + b0 + 4)*H_);
      #pragma unroll
      for (int p=0;p<4;p++)
        vA[p] = __hip_atomic_load(srcA + p*256 + tid,
                                  __ATOMIC_RELAXED, __HIP_MEMORY_SCOPE_AGENT);
      #pragma unroll
      for (int p=0;p<4;p++)
        vB[p] = __hip_atomic_load(srcB + p*256 + tid,
                                  __ATOMIC_RELAXED, __HIP_MEMORY_SCOPE_AGENT);
      unsigned long long* dA = (unsigned long long*)hlA;
      unsigned long long* dB = (unsigned long long*)hlB;
      #pragma unroll
      for (int p=0;p<4;p++) dA[p*256+tid] = vA[p];
      #pragma unroll
      for (int p=0;p<4;p++) dB[p*256+tid] = vB[p];
    }
    __syncthreads();   // S4: LDS h buffers ready for next step
  }
}

// ---------------------------------------------------------------------------
// Kernel 3: scores[r] = sum_h' v[h'] * tanh( sum_h hs[r][h]*aW[h'][h] + ab[h'] )
// M=32768 rows, N=512 (reduced, fused), K=512. 128-row tiles, 4 N-subtiles.
// ---------------------------------------------------------------------------
__global__ __launch_bounds__(256, 2) void attn_scores(
    const float* __restrict__ hs, const float* __restrict__ aW,
    const float* __restrict__ ab, const float* __restrict__ av,
    float* __restrict__ scores)
{
  __shared__ __align__(16) float As[32][132];
  __shared__ __align__(16) float Bs[32][132];
  const int tid = threadIdx.x;
  const int tx = tid & 15, ty = tid >> 4;
  const int r0 = blockIdx.x * 128;

  float sacc[8];
  #pragma unroll
  for (int i=0;i<8;i++) sacc[i]=0.f;

  for (int ntl=0; ntl<4; ntl++){
    const int n0 = ntl*128;
    float acc[8][8];
    #pragma unroll
    for (int i=0;i<8;i++)
      #pragma unroll
      for (int j2=0;j2<8;j2++) acc[i][j2]=0.f;

    for (int kt=0; kt<H_; kt+=32){
      #pragma unroll
      for (int p=0;p<4;p++){
        int f4 = p*256+tid; int m = f4>>3; int kf = f4&7;
        const float4 va = *(const float4*)(hs + ((size_t)(r0+m))*H_ + kt + kf*4);
        As[kf*4+0][m]=va.x; As[kf*4+1][m]=va.y; As[kf*4+2][m]=va.z; As[kf*4+3][m]=va.w;
        const float4 vb = *(const float4*)(aW + ((size_t)(n0+m))*H_ + kt + kf*4);
        Bs[kf*4+0][m]=vb.x; Bs[kf*4+1][m]=vb.y; Bs[kf*4+2][m]=vb.z; Bs[kf*4+3][m]=vb.w;
      }
      __syncthreads();
      #pragma unroll
      for (int kk=0;kk<32;kk++){
        float a[8], b[8];
        *(float4*)&a[0] = *(const float4*)&As[kk][ty*8];
        *(float4*)&a[4] = *(const float4*)&As[kk][ty*8+4];
        *(float4*)&b[0] = *(const float4*)&Bs[kk][tx*8];
        *(float4*)&b[4] = *(const float4*)&Bs[kk][tx*8+4];
        #pragma unroll
        for (int i=0;i<8;i++)
          #pragma unroll
          for (int j2=0;j2<8;j2++)
            acc[i][j2] += a[i]*b[j2];
      }
      __syncthreads();
    }
    float vv[8], bb2[8];
    #pragma unroll
    for (int j2=0;j2<8;j2++){ vv[j2]=av[n0+tx*8+j2]; bb2[j2]=ab[n0+tx*8+j2]; }
    #pragma unroll
    for (int i=0;i<8;i++){
      #pragma unroll
      for (int j2=0;j2<8;j2++){
        sacc[i] += tanh_f(acc[i][j2] + bb2[j2]) * vv[j2];
      }
    }
  }
  // reduce over tx (low 4 lane bits)
  #pragma unroll
  for (int i=0;i<8;i++){
    sacc[i] += __shfl_xor(sacc[i],1,64); sacc[i] += __shfl_xor(sacc[i],2,64);
    sacc[i] += __shfl_xor(sacc[i],4,64); sacc[i] += __shfl_xor(sacc[i],8,64);
  }
  if (tx == 0){
    #pragma unroll
    for (int i=0;i<8;i++) scores[r0 + ty*8 + i] = sacc[i];
  }
}

// ---------------------------------------------------------------------------
// Kernel 4: per-batch softmax over t, then context[b][h] = sum_t w[t]*hs[t][b][h]
// ---------------------------------------------------------------------------
__global__ __launch_bounds__(256, 2) void softmax_ctx(
    const float* __restrict__ scores, const float* __restrict__ hs,
    float* __restrict__ out)
{
  const int b = blockIdx.x;
  const int tid = threadIdx.x;
  __shared__ float wl[512];
  __shared__ float rmax[4];
  __shared__ float rsum[4];

  float s0 = scores[(size_t)tid*B_ + b];
  float s1 = scores[(size_t)(tid+256)*B_ + b];
  float mx = fmaxf(s0,s1);
  #pragma unroll
  for (int s=32;s>=1;s>>=1) mx = fmaxf(mx, __shfl_xor(mx, s, 64));
  if ((tid & 63)==0) rmax[tid>>6]=mx;
  __syncthreads();
  mx = fmaxf(fmaxf(rmax[0],rmax[1]), fmaxf(rmax[2],rmax[3]));
  float e0 = __expf(s0-mx), e1 = __expf(s1-mx);
  float sm = e0+e1;
  #pragma unroll
  for (int s=32;s>=1;s>>=1) sm += __shfl_xor(sm, s, 64);
  if ((tid & 63)==0) rsum[tid>>6]=sm;
  __syncthreads();
  sm = rsum[0]+rsum[1]+rsum[2]+rsum[3];
  float inv = 1.f/sm;
  wl[tid] = e0*inv; wl[tid+256] = e1*inv;
  __syncthreads();

  float2 acc = {0.f, 0.f};
  const int h0 = tid*2;
  #pragma unroll 4
  for (int t=0;t<T_;t++){
    float wt = wl[t];
    float2 hv = *(const float2*)(hs + ((size_t)t*B_ + b)*H_ + h0);
    acc.x += wt*hv.x; acc.y += wt*hv.y;
  }
  *(float2*)(out + (size_t)b*H_ + h0) = acc;
}

// ---------------------------------------------------------------------------
extern "C" void kernel_launch(void* const* d_in, const int* in_sizes, int n_in,
                              void* d_out, int out_size, void* d_ws, size_t ws_size,
                              hipStream_t stream)
{
  const float* x   = (const float*)d_in[0];
  const float* Wih = (const float*)d_in[1];
  const float* Whh = (const float*)d_in[2];
  const float* bih = (const float*)d_in[3];
  const float* bhh = (const float*)d_in[4];
  const float* aW  = (const float*)d_in[5];
  const float* ab  = (const float*)d_in[6];
  const float* av  = (const float*)d_in[7];
  float* out = (float*)d_out;

  char* ws = (char*)d_ws;
  float*    xproj = (float*)(ws + XPROJ_OFF);
  float*    hs    = (float*)(ws + HS_OFF);
  float*    sc    = (float*)(ws + SC_OFF);   // aliases xproj (dead after scan)
  unsigned* bar   = (unsigned*)d_out;        // 64 KB, fully overwritten by softmax_ctx

  zero_bar   <<<BAR_WORDS/256, 256, 0, stream>>>(bar);
  xproj_gemm <<<dim3(256,12),  256, 0, stream>>>(x, Wih, bih, xproj);
  scan_kernel<<<256,           256, 0, stream>>>(Whh, bhh, xproj, hs, bar);
  attn_scores<<<dim3(256),     256, 0, stream>>>(hs, aW, ab, av, sc);
  softmax_ctx<<<64,            256, 0, stream>>>(sc, hs, out);
}